// Round 1
// baseline (25693.057 us; speedup 1.0000x reference)
//
#include <hip/hip_runtime.h>
#include <hip/hip_fp16.h>

typedef unsigned short u16;
typedef short s16x8 __attribute__((ext_vector_type(8)));
typedef float f32x4 __attribute__((ext_vector_type(4)));

#define BB   32
#define SS   1024
#define DD   512
#define G4   2048
#define MAXW 256

__device__ __forceinline__ u16 f2bf(float f){
  unsigned int u = __float_as_uint(f);
  u += 0x7fff + ((u >> 16) & 1);           // RNE
  return (u16)(u >> 16);
}
__device__ __forceinline__ float bf2f(u16 h){
  return __uint_as_float(((unsigned int)h) << 16);
}
__device__ __forceinline__ float sigm(float x){ return 1.f/(1.f + __expf(-x)); }
__device__ __forceinline__ float ftanh(float x){
  float ax = fabsf(x);
  float e = __expf(-2.f*ax);               // in (0,1], never overflows
  float t = (1.f - e)/(1.f + e);
  return copysignf(t, x);
}

// ---------------- prep: fp32 weights -> bf16; fused permuted bias ----------
// bias_perm[l][n] = b_ih[l][g]+b_hh[l][g], g = (n&3)*512 + (n>>2)  (gate-minor)
__global__ void k_prep(const float* __restrict__ Wih, const float* __restrict__ Whh,
                       const float* __restrict__ bih, const float* __restrict__ bhh,
                       u16* __restrict__ Wih_b, u16* __restrict__ Whh_b,
                       float* __restrict__ biasp){
  long i = (long)blockIdx.x*blockDim.x + threadIdx.x;
  long n = 2l*G4*DD;
  long stride = (long)gridDim.x*blockDim.x;
  for (long k = i; k < n; k += stride){
    Wih_b[k] = f2bf(Wih[k]);
    Whh_b[k] = f2bf(Whh[k]);
  }
  for (long k = i; k < 2*G4; k += stride){
    int lyr = (int)(k / G4), nn = (int)(k % G4);
    int col = nn >> 2, q = nn & 3;
    int g = q*DD + col;
    biasp[k] = bih[lyr*G4 + g] + bhh[lyr*G4 + g];
  }
}

// ---------------- embedding gather -> bf16 [B*S][D] ------------------------
__global__ void k_embed(const int* __restrict__ x, const float* __restrict__ emb,
                        u16* __restrict__ out){
  int bs = blockIdx.x;                     // 0..32767
  int tok = x[bs];
  const float* src = emb + (size_t)tok * DD;
  u16* dst = out + (size_t)bs * DD;
  for (int d = threadIdx.x; d < DD; d += blockDim.x) dst[d] = f2bf(src[d]);
}

// ---------------- x-projection GEMM --------------------------------------
// A[M=32768][512] bf16 (tokens), Bw = W_ih layer [2048][512] bf16.
// Output xp[m][n] fp16 with n in GATE-MINOR permuted order: n = col*4+q,
// i.e. B-rows are loaded permuted: W_ih row = (n&3)*512 + (n>>2).
// Includes bias (biasp, same permutation). 128x128 tile, BK=64, 4 waves,
// XOR-swizzled LDS (reg-staged; global_load_lds is a later-round upgrade).
#define Bb_M 128
#define Bb_N 128
#define Bb_K 64
__global__ __launch_bounds__(256) void k_xproj(const u16* __restrict__ A,
                                               const u16* __restrict__ Bw,
                                               const float* __restrict__ biasp,
                                               __half* __restrict__ xp){
  __shared__ u16 As[Bb_M*Bb_K];
  __shared__ u16 Bs[Bb_N*Bb_K];
  const int tid = threadIdx.x;
  const int lane = tid & 63, wv = tid >> 6;
  const int bn = blockIdx.x;               // 0..15
  const int bm = blockIdx.y;               // 0..255 (consecutive n-tiles share A tile in time)
  const int m0 = bm * Bb_M, n0 = bn * Bb_N;
  const int wm = wv >> 1, wn = wv & 1;     // 2x2 waves of 64x64
  f32x4 acc[4][4] = {};

  for (int k0 = 0; k0 < DD; k0 += Bb_K){
    #pragma unroll
    for (int i = 0; i < 4; i++){
      int sg = tid + 256*i;                // 0..1023 : 128 rows x 8 segs(16B)
      int r = sg >> 3, c = sg & 7;
      int slot = c ^ (r & 7);
      const u16* gpa = A + (size_t)(m0 + r)*DD + k0 + c*8;
      *(int4*)((char*)As + r*128 + slot*16) = *(const int4*)gpa;
      int rn = n0 + r;
      int col = rn >> 2, q = rn & 3;
      const u16* gpb = Bw + (size_t)(q*DD + col)*DD + k0 + c*8;
      *(int4*)((char*)Bs + r*128 + slot*16) = *(const int4*)gpb;
    }
    __syncthreads();
    #pragma unroll
    for (int kk = 0; kk < 2; kk++){
      s16x8 af[4], bfr[4];
      #pragma unroll
      for (int fm = 0; fm < 4; fm++){
        int row = wm*64 + fm*16 + (lane & 15);
        int byt = row*128 + ((kk*64 + (lane>>4)*16) ^ ((row & 7) << 4));
        af[fm] = *(const s16x8*)((const char*)As + byt);
      }
      #pragma unroll
      for (int fn = 0; fn < 4; fn++){
        int row = wn*64 + fn*16 + (lane & 15);
        int byt = row*128 + ((kk*64 + (lane>>4)*16) ^ ((row & 7) << 4));
        bfr[fn] = *(const s16x8*)((const char*)Bs + byt);
      }
      #pragma unroll
      for (int fm = 0; fm < 4; fm++)
        #pragma unroll
        for (int fn = 0; fn < 4; fn++)
          acc[fm][fn] = __builtin_amdgcn_mfma_f32_16x16x32_bf16(af[fm], bfr[fn], acc[fm][fn], 0, 0, 0);
    }
    __syncthreads();
  }
  // epilogue: C row=(lane>>4)*4+reg -> m ; col=lane&15 -> n  (m89 mapping)
  #pragma unroll
  for (int fn = 0; fn < 4; fn++){
    int n = n0 + wn*64 + fn*16 + (lane & 15);
    float badd = biasp[n];
    #pragma unroll
    for (int fm = 0; fm < 4; fm++){
      #pragma unroll
      for (int r = 0; r < 4; r++){
        int m = m0 + wm*64 + fm*16 + (lane>>4)*4 + r;
        xp[(size_t)m*G4 + n] = __float2half(acc[fm][fn][r] + badd);
      }
    }
  }
}

// ---------------- persistent LSTM recurrence ------------------------------
// 256 WGs x 64 threads. WG = (grp: batch half 16, w: 4 h-cols, all 4 gates).
// W_hh slice [16 rows][512] bf16 resident in LDS (XOR-swizzled), A-fragments
// hoisted to registers for the whole kernel. Per step: 16 chained MFMAs
// (A=W rows, B=h), lane owns exactly one (batch,col): C col=lane&15=batch,
// C rows (lane>>4 selects col, reg selects gate i/f/g/o). Double-buffered
// global hbuf + per-group 128-WG flag barrier (release store/acquire fence).
__global__ __launch_bounds__(64) void k_recur(const __half* __restrict__ xp,
                                              const u16* __restrict__ Whh_b,
                                              u16* __restrict__ hbuf,
                                              u16* __restrict__ h_seq,
                                              unsigned int* flags){
  __shared__ u16 Wl[16*512];
  const int lane = threadIdx.x;
  const int wg = blockIdx.x;
  const int grp = wg >> 7;                 // 0/1: batch 0-15 / 16-31
  const int w = wg & 127;                  // 0..127: cols [4w,4w+4)
  const int bb = grp * 16;
  const int col0 = w * 4;

  // stage Whh slice: LDS row sr = cc*4+q  <->  Whh row q*512 + col0 + cc
  for (int sr = 0; sr < 16; sr++){
    int cc = sr >> 2, q = sr & 3;
    const u16* gp = Whh_b + (size_t)(q*DD + col0 + cc)*DD + lane*8;
    int4 v = *(const int4*)gp;
    *(int4*)((char*)Wl + sr*1024 + ((lane*16) ^ ((sr & 7) << 4))) = v;
  }
  __syncthreads();

  s16x8 afr[16];
  {
    int sr = lane & 15;
    #pragma unroll
    for (int kk = 0; kk < 16; kk++){
      int byt = sr*1024 + (((kk*32 + (lane>>4)*8)*2) ^ ((sr & 7) << 4));
      afr[kk] = *(const s16x8*)((const char*)Wl + byt);
    }
  }

  const int b_l = lane & 15;
  const int cc4 = lane >> 4;
  const int myb = bb + b_l;                // this lane's batch row
  const int mycol = col0 + cc4;            // this lane's h column
  float c_state = 0.f;
  uint2 xv = *(const uint2*)(xp + ((size_t)myb*SS + 0)*G4 + mycol*4);
  unsigned int* gflags = flags + grp*128;

  for (int t = 0; t < SS; t++){
    f32x4 acc = {0.f, 0.f, 0.f, 0.f};
    if (t > 0){
      const int rb = t & 1;
      const u16* hb = hbuf + (size_t)(rb*BB + myb)*DD + cc4*8;
      s16x8 bfr[16];
      #pragma unroll
      for (int kk = 0; kk < 16; kk++)
        bfr[kk] = *(const s16x8*)(hb + kk*32);
      #pragma unroll
      for (int kk = 0; kk < 16; kk++)
        acc = __builtin_amdgcn_mfma_f32_16x16x32_bf16(afr[kk], bfr[kk], acc, 0, 0, 0);
    }
    const __half* xq = (const __half*)&xv;
    float ig = sigm (acc[0] + __half2float(xq[0]));
    float fg = sigm (acc[1] + __half2float(xq[1]));
    float gg = ftanh(acc[2] + __half2float(xq[2]));
    float og = sigm (acc[3] + __half2float(xq[3]));
    c_state = fg*c_state + ig*gg;
    float h = og * ftanh(c_state);
    u16 h16 = f2bf(h);
    const int wb = (t + 1) & 1;
    hbuf[(size_t)(wb*BB + myb)*DD + mycol] = h16;
    h_seq[((size_t)myb*SS + t)*DD + mycol] = h16;

    if (t + 1 < SS){
      if (lane == 0)
        __hip_atomic_store(&gflags[w], (unsigned int)(t + 1),
                           __ATOMIC_RELEASE, __HIP_MEMORY_SCOPE_AGENT);
      // prefetch next step's x-proj AFTER publish so its latency hides in the poll
      xv = *(const uint2*)(xp + ((size_t)myb*SS + (t + 1))*G4 + mycol*4);
      unsigned int tgt = t + 1;
      int ok;
      do {
        unsigned int v0 = __hip_atomic_load(&gflags[lane],      __ATOMIC_RELAXED, __HIP_MEMORY_SCOPE_AGENT);
        unsigned int v1 = __hip_atomic_load(&gflags[lane + 64], __ATOMIC_RELAXED, __HIP_MEMORY_SCOPE_AGENT);
        ok = (v0 >= tgt) && (v1 >= tgt);
      } while (!__all(ok));
      __builtin_amdgcn_fence(__ATOMIC_ACQUIRE, "agent");
    }
  }
}

// ---------------- ragged mean-pool + span head ----------------------------
// one wave per (b, word): binary search the sorted token_word_id row, sum
// h (bf16) over the span, dot with W_out, + b_out -> logits.
__global__ __launch_bounds__(64) void k_pool(const u16* __restrict__ h_seq,
                                             const int* __restrict__ twid,
                                             const float* __restrict__ Wout,
                                             const float* __restrict__ bout,
                                             float* __restrict__ out){
  int bw = blockIdx.x;                     // 0..8191
  int b = bw >> 8, w = bw & 255;
  const int* tw = twid + b*SS;
  __shared__ int s_lo, s_hi;
  if (threadIdx.x == 0){
    int l = 0, r = SS;
    while (l < r){ int m = (l + r) >> 1; if (tw[m] < w) l = m + 1; else r = m; }
    s_lo = l;
    r = SS;
    while (l < r){ int m = (l + r) >> 1; if (tw[m] < w + 1) l = m + 1; else r = m; }
    s_hi = l;
  }
  __syncthreads();
  int lo = s_lo, hi = s_hi, cnt = hi - lo;
  int lane = threadIdx.x;
  float p0 = 0.f, p1 = 0.f;
  if (cnt > 0){
    float sum[8] = {0.f,0.f,0.f,0.f,0.f,0.f,0.f,0.f};
    for (int t = lo; t < hi; t++){
      const u16* hp = h_seq + ((size_t)b*SS + t)*DD + lane*8;
      int4 v = *(const int4*)hp;
      const u16* u = (const u16*)&v;
      #pragma unroll
      for (int j = 0; j < 8; j++) sum[j] += bf2f(u[j]);
    }
    float inv = 1.f/(float)cnt;
    #pragma unroll
    for (int j = 0; j < 8; j++){
      float pv = sum[j]*inv;
      int d = lane*8 + j;
      p0 += pv * Wout[d];
      p1 += pv * Wout[DD + d];
    }
  }
  #pragma unroll
  for (int off = 32; off; off >>= 1){
    p0 += __shfl_down(p0, off);
    p1 += __shfl_down(p1, off);
  }
  if (lane == 0){
    out[bw*2 + 0] = p0 + bout[0];
    out[bw*2 + 1] = p1 + bout[1];
  }
}

// ---------------- NLL loss over 8192 spans --------------------------------
__global__ __launch_bounds__(256) void k_loss(const float* __restrict__ logits,
                                              const int* __restrict__ labels,
                                              float* __restrict__ out_loss){
  __shared__ float red[256];
  float acc = 0.f;
  for (int i = threadIdx.x; i < BB*MAXW; i += 256){
    float z0 = logits[i*2], z1 = logits[i*2 + 1];
    float m = fmaxf(z0, z1);
    float lse = m + __logf(__expf(z0 - m) + __expf(z1 - m));
    float zl = labels[i] ? z1 : z0;
    acc += (lse - zl);
  }
  red[threadIdx.x] = acc;
  __syncthreads();
  for (int s2 = 128; s2; s2 >>= 1){
    if (threadIdx.x < s2) red[threadIdx.x] += red[threadIdx.x + s2];
    __syncthreads();
  }
  if (threadIdx.x == 0) out_loss[0] = red[0] / (float)(BB*MAXW);
}

extern "C" void kernel_launch(void* const* d_in, const int* in_sizes, int n_in,
                              void* d_out, int out_size, void* d_ws, size_t ws_size,
                              hipStream_t stream){
  (void)in_sizes; (void)n_in; (void)out_size;
  const int*   x      = (const int*)  d_in[0];
  const int*   labels = (const int*)  d_in[1];
  const int*   twid   = (const int*)  d_in[2];
  const float* emb    = (const float*)d_in[3];
  const float* Wih    = (const float*)d_in[4];
  const float* Whh    = (const float*)d_in[5];
  const float* bih    = (const float*)d_in[6];
  const float* bhh    = (const float*)d_in[7];
  const float* Wout   = (const float*)d_in[8];
  const float* bout   = (const float*)d_in[9];
  float* out = (float*)d_out;

  char* ws = (char*)d_ws;
  size_t off = 0;
  u16*   h_io   = (u16*)  (ws + off); off += (size_t)BB*SS*DD*2;   // 32 MB
  u16*   h_seq1 = (u16*)  (ws + off); off += (size_t)BB*SS*DD*2;   // 32 MB
  u16*   h_seq2 = (u16*)  (ws + off); off += (size_t)BB*SS*DD*2;   // 32 MB
  __half* xp    = (__half*)(ws + off); off += (size_t)BB*SS*G4*2;  // 128 MB
  u16*   Wih_b  = (u16*)  (ws + off); off += (size_t)2*G4*DD*2;    // 4 MB
  u16*   Whh_b  = (u16*)  (ws + off); off += (size_t)2*G4*DD*2;    // 4 MB
  float* biasp  = (float*)(ws + off); off += (size_t)2*G4*4;
  u16*   hbuf   = (u16*)  (ws + off); off += (size_t)2*BB*DD*2;
  unsigned int* flags = (unsigned int*)(ws + off); off += 256*4;
  (void)ws_size; // requires ~233 MB of workspace

  k_prep<<<2048, 256, 0, stream>>>(Wih, Whh, bih, bhh, Wih_b, Whh_b, biasp);
  k_embed<<<BB*SS, 256, 0, stream>>>(x, emb, h_io);

  const u16* lin = h_io;
  u16* louts[2] = {h_seq1, h_seq2};
  for (int l = 0; l < 2; l++){
    k_xproj<<<dim3(16, 256), 256, 0, stream>>>(lin, Wih_b + (size_t)l*G4*DD,
                                               biasp + (size_t)l*G4, xp);
    hipMemsetAsync(flags, 0, 256*sizeof(unsigned int), stream);
    k_recur<<<256, 64, 0, stream>>>(xp, Whh_b + (size_t)l*G4*DD, hbuf, louts[l], flags);
    lin = louts[l];
  }

  k_pool<<<BB*MAXW, 64, 0, stream>>>(h_seq2, twid, Wout, bout, out);
  k_loss<<<1, 256, 0, stream>>>(out, labels, out + BB*MAXW*2);
}

// Round 2
// 13634.471 us; speedup vs baseline: 1.8844x; 1.8844x over previous
//
#include <hip/hip_runtime.h>
#include <hip/hip_fp16.h>

typedef unsigned short u16;
typedef short s16x8 __attribute__((ext_vector_type(8)));
typedef float f32x4 __attribute__((ext_vector_type(4)));

#define BB   32
#define SS   1024
#define DD   512
#define G4   2048
#define MAXW 256

__device__ __forceinline__ u16 f2bf(float f){
  unsigned int u = __float_as_uint(f);
  u += 0x7fff + ((u >> 16) & 1);           // RNE
  return (u16)(u >> 16);
}
__device__ __forceinline__ float bf2f(u16 h){
  return __uint_as_float(((unsigned int)h) << 16);
}
__device__ __forceinline__ float sigm(float x){ return 1.f/(1.f + __expf(-x)); }
__device__ __forceinline__ float ftanh(float x){
  float ax = fabsf(x);
  float e = __expf(-2.f*ax);               // in (0,1], never overflows
  float t = (1.f - e)/(1.f + e);
  return copysignf(t, x);
}

// ---------------- prep: fp32 weights -> bf16; fused permuted bias ----------
// bias_perm[l][n] = b_ih[l][g]+b_hh[l][g], g = (n&3)*512 + (n>>2)  (gate-minor)
__global__ void k_prep(const float* __restrict__ Wih, const float* __restrict__ Whh,
                       const float* __restrict__ bih, const float* __restrict__ bhh,
                       u16* __restrict__ Wih_b, u16* __restrict__ Whh_b,
                       float* __restrict__ biasp){
  long i = (long)blockIdx.x*blockDim.x + threadIdx.x;
  long n = 2l*G4*DD;
  long stride = (long)gridDim.x*blockDim.x;
  for (long k = i; k < n; k += stride){
    Wih_b[k] = f2bf(Wih[k]);
    Whh_b[k] = f2bf(Whh[k]);
  }
  for (long k = i; k < 2*G4; k += stride){
    int lyr = (int)(k / G4), nn = (int)(k % G4);
    int col = nn >> 2, q = nn & 3;
    int g = q*DD + col;
    biasp[k] = bih[lyr*G4 + g] + bhh[lyr*G4 + g];
  }
}

// ---------------- embedding gather -> bf16 [B*S][D] ------------------------
__global__ void k_embed(const int* __restrict__ x, const float* __restrict__ emb,
                        u16* __restrict__ out){
  int bs = blockIdx.x;                     // 0..32767
  int tok = x[bs];
  const float* src = emb + (size_t)tok * DD;
  u16* dst = out + (size_t)bs * DD;
  for (int d = threadIdx.x; d < DD; d += blockDim.x) dst[d] = f2bf(src[d]);
}

// ---------------- x-projection GEMM --------------------------------------
// A[M=32768][512] bf16 (tokens), Bw = W_ih layer [2048][512] bf16.
// Output xp[m][n] fp16 with n in GATE-MINOR permuted order: n = col*4+q,
// i.e. B-rows are loaded permuted: W_ih row = (n&3)*512 + (n>>2).
// Includes bias (biasp, same permutation). 128x128 tile, BK=64, 4 waves,
// XOR-swizzled LDS.
#define Bb_M 128
#define Bb_N 128
#define Bb_K 64
__global__ __launch_bounds__(256) void k_xproj(const u16* __restrict__ A,
                                               const u16* __restrict__ Bw,
                                               const float* __restrict__ biasp,
                                               __half* __restrict__ xp){
  __shared__ u16 As[Bb_M*Bb_K];
  __shared__ u16 Bs[Bb_N*Bb_K];
  const int tid = threadIdx.x;
  const int lane = tid & 63, wv = tid >> 6;
  const int bn = blockIdx.x;               // 0..15
  const int bm = blockIdx.y;               // 0..255
  const int m0 = bm * Bb_M, n0 = bn * Bb_N;
  const int wm = wv >> 1, wn = wv & 1;     // 2x2 waves of 64x64
  f32x4 acc[4][4] = {};

  for (int k0 = 0; k0 < DD; k0 += Bb_K){
    #pragma unroll
    for (int i = 0; i < 4; i++){
      int sg = tid + 256*i;                // 0..1023 : 128 rows x 8 segs(16B)
      int r = sg >> 3, c = sg & 7;
      int slot = c ^ (r & 7);
      const u16* gpa = A + (size_t)(m0 + r)*DD + k0 + c*8;
      *(int4*)((char*)As + r*128 + slot*16) = *(const int4*)gpa;
      int rn = n0 + r;
      int col = rn >> 2, q = rn & 3;
      const u16* gpb = Bw + (size_t)(q*DD + col)*DD + k0 + c*8;
      *(int4*)((char*)Bs + r*128 + slot*16) = *(const int4*)gpb;
    }
    __syncthreads();
    #pragma unroll
    for (int kk = 0; kk < 2; kk++){
      s16x8 af[4], bfr[4];
      #pragma unroll
      for (int fm = 0; fm < 4; fm++){
        int row = wm*64 + fm*16 + (lane & 15);
        int byt = row*128 + ((kk*64 + (lane>>4)*16) ^ ((row & 7) << 4));
        af[fm] = *(const s16x8*)((const char*)As + byt);
      }
      #pragma unroll
      for (int fn = 0; fn < 4; fn++){
        int row = wn*64 + fn*16 + (lane & 15);
        int byt = row*128 + ((kk*64 + (lane>>4)*16) ^ ((row & 7) << 4));
        bfr[fn] = *(const s16x8*)((const char*)Bs + byt);
      }
      #pragma unroll
      for (int fm = 0; fm < 4; fm++)
        #pragma unroll
        for (int fn = 0; fn < 4; fn++)
          acc[fm][fn] = __builtin_amdgcn_mfma_f32_16x16x32_bf16(af[fm], bfr[fn], acc[fm][fn], 0, 0, 0);
    }
    __syncthreads();
  }
  // epilogue: C row=(lane>>4)*4+reg -> m ; col=lane&15 -> n  (m89 mapping)
  #pragma unroll
  for (int fn = 0; fn < 4; fn++){
    int n = n0 + wn*64 + fn*16 + (lane & 15);
    float badd = biasp[n];
    #pragma unroll
    for (int fm = 0; fm < 4; fm++){
      #pragma unroll
      for (int r = 0; r < 4; r++){
        int m = m0 + wm*64 + fm*16 + (lane>>4)*4 + r;
        xp[(size_t)m*G4 + n] = __float2half(acc[fm][fn][r] + badd);
      }
    }
  }
}

// ---------------- persistent LSTM recurrence ------------------------------
// 256 WGs x 64 threads (1 wave each). WG = (grp: batch half 16, w: 4 h-cols,
// all 4 gates). W_hh slice in LDS -> A-fragments hoisted to registers.
// Per step: 16 chained MFMAs; lane owns one (batch,col).
// Cross-WG data path is PER-ACCESS coherent (no cache-wide fences!):
//   - h written as packed 4B relaxed AGENT atomic stores (write-through)
//   - s_waitcnt vmcnt(0) drains them, then relaxed AGENT flag store
//   - readers poll relaxed AGENT flag loads, read h via 8B relaxed AGENT
//     atomic loads (bypass stale per-XCD L2 for just those lines)
// This avoids the buffer_wbl2/buffer_inv per step that the release/acquire
// fence pair caused (12.5us/step, 300MB L2 refetch in round 1).
__global__ __launch_bounds__(64) void k_recur(const __half* __restrict__ xp,
                                              const u16* __restrict__ Whh_b,
                                              u16* __restrict__ hbuf,
                                              u16* __restrict__ h_seq,
                                              unsigned int* flags){
  __shared__ u16 Wl[16*512];
  const int lane = threadIdx.x;
  const int wg = blockIdx.x;
  const int grp = wg >> 7;                 // 0/1: batch 0-15 / 16-31
  const int w = wg & 127;                  // 0..127: cols [4w,4w+4)
  const int bb = grp * 16;
  const int col0 = w * 4;

  // stage Whh slice: LDS row sr = cc*4+q  <->  Whh row q*512 + col0 + cc
  for (int sr = 0; sr < 16; sr++){
    int cc = sr >> 2, q = sr & 3;
    const u16* gp = Whh_b + (size_t)(q*DD + col0 + cc)*DD + lane*8;
    int4 v = *(const int4*)gp;
    *(int4*)((char*)Wl + sr*1024 + ((lane*16) ^ ((sr & 7) << 4))) = v;
  }
  __syncthreads();

  s16x8 afr[16];
  {
    int sr = lane & 15;
    #pragma unroll
    for (int kk = 0; kk < 16; kk++){
      int byt = sr*1024 + (((kk*32 + (lane>>4)*8)*2) ^ ((sr & 7) << 4));
      afr[kk] = *(const s16x8*)((const char*)Wl + byt);
    }
  }

  const int b_l = lane & 15;
  const int cc4 = lane >> 4;
  const int myb = bb + b_l;                // this lane's batch row
  const int mycol = col0 + cc4;            // this lane's h column
  float c_state = 0.f;
  uint2 xv = *(const uint2*)(xp + ((size_t)myb*SS + 0)*G4 + mycol*4);
  unsigned int* gflags = flags + grp*128;

  for (int t = 0; t < SS; t++){
    f32x4 acc = {0.f, 0.f, 0.f, 0.f};
    if (t > 0){
      const int rb = t & 1;
      const u16* hb = hbuf + (size_t)(rb*BB + myb)*DD + cc4*8;
      s16x8 bfr[16];
      #pragma unroll
      for (int kk = 0; kk < 16; kk++){
        union { s16x8 v; unsigned long long q[2]; } uu;
        uu.q[0] = __hip_atomic_load((const unsigned long long*)(hb + kk*32),
                                    __ATOMIC_RELAXED, __HIP_MEMORY_SCOPE_AGENT);
        uu.q[1] = __hip_atomic_load((const unsigned long long*)(hb + kk*32 + 4),
                                    __ATOMIC_RELAXED, __HIP_MEMORY_SCOPE_AGENT);
        bfr[kk] = uu.v;
      }
      #pragma unroll
      for (int kk = 0; kk < 16; kk++)
        acc = __builtin_amdgcn_mfma_f32_16x16x32_bf16(afr[kk], bfr[kk], acc, 0, 0, 0);
    }
    const __half* xq = (const __half*)&xv;
    float ig = sigm (acc[0] + __half2float(xq[0]));
    float fg = sigm (acc[1] + __half2float(xq[1]));
    float gg = ftanh(acc[2] + __half2float(xq[2]));
    float og = sigm (acc[3] + __half2float(xq[3]));
    c_state = fg*c_state + ig*gg;
    float h = og * ftanh(c_state);
    u16 h16 = f2bf(h);
    // pack 2 consecutive cols (cc4 even lane + its cc4+1 partner) into 4B
    unsigned int hx = (unsigned int)h16;
    unsigned int other = (unsigned int)__shfl((int)hx, (lane + 16) & 63) & 0xffffu;
    unsigned int packed = hx | (other << 16);
    const int wb = (t + 1) & 1;
    if ((cc4 & 1) == 0){
      __hip_atomic_store((unsigned int*)(hbuf + (size_t)(wb*BB + myb)*DD + mycol),
                         packed, __ATOMIC_RELAXED, __HIP_MEMORY_SCOPE_AGENT);
      *(unsigned int*)(h_seq + ((size_t)myb*SS + t)*DD + mycol) = packed;
    }

    if (t + 1 < SS){
      // drain h stores (acked at coherence point), then publish flag
      asm volatile("s_waitcnt vmcnt(0)" ::: "memory");
      if (lane == 0)
        __hip_atomic_store(&gflags[w], (unsigned int)(t + 1),
                           __ATOMIC_RELAXED, __HIP_MEMORY_SCOPE_AGENT);
      // prefetch next step's x-proj; its L2-hit latency hides in the poll
      xv = *(const uint2*)(xp + ((size_t)myb*SS + (t + 1))*G4 + mycol*4);
      unsigned int tgt = t + 1;
      int ok;
      do {
        unsigned int v0 = __hip_atomic_load(&gflags[lane],      __ATOMIC_RELAXED, __HIP_MEMORY_SCOPE_AGENT);
        unsigned int v1 = __hip_atomic_load(&gflags[lane + 64], __ATOMIC_RELAXED, __HIP_MEMORY_SCOPE_AGENT);
        ok = (v0 >= tgt) && (v1 >= tgt);
      } while (!__all(ok));
      asm volatile("" ::: "memory");       // compiler barrier only
    }
  }
}

// ---------------- ragged mean-pool + span head ----------------------------
__global__ __launch_bounds__(64) void k_pool(const u16* __restrict__ h_seq,
                                             const int* __restrict__ twid,
                                             const float* __restrict__ Wout,
                                             const float* __restrict__ bout,
                                             float* __restrict__ out){
  int bw = blockIdx.x;                     // 0..8191
  int b = bw >> 8, w = bw & 255;
  const int* tw = twid + b*SS;
  __shared__ int s_lo, s_hi;
  if (threadIdx.x == 0){
    int l = 0, r = SS;
    while (l < r){ int m = (l + r) >> 1; if (tw[m] < w) l = m + 1; else r = m; }
    s_lo = l;
    r = SS;
    while (l < r){ int m = (l + r) >> 1; if (tw[m] < w + 1) l = m + 1; else r = m; }
    s_hi = l;
  }
  __syncthreads();
  int lo = s_lo, hi = s_hi, cnt = hi - lo;
  int lane = threadIdx.x;
  float p0 = 0.f, p1 = 0.f;
  if (cnt > 0){
    float sum[8] = {0.f,0.f,0.f,0.f,0.f,0.f,0.f,0.f};
    for (int t = lo; t < hi; t++){
      const u16* hp = h_seq + ((size_t)b*SS + t)*DD + lane*8;
      int4 v = *(const int4*)hp;
      const u16* u = (const u16*)&v;
      #pragma unroll
      for (int j = 0; j < 8; j++) sum[j] += bf2f(u[j]);
    }
    float inv = 1.f/(float)cnt;
    #pragma unroll
    for (int j = 0; j < 8; j++){
      float pv = sum[j]*inv;
      int d = lane*8 + j;
      p0 += pv * Wout[d];
      p1 += pv * Wout[DD + d];
    }
  }
  #pragma unroll
  for (int off = 32; off; off >>= 1){
    p0 += __shfl_down(p0, off);
    p1 += __shfl_down(p1, off);
  }
  if (lane == 0){
    out[bw*2 + 0] = p0 + bout[0];
    out[bw*2 + 1] = p1 + bout[1];
  }
}

// ---------------- NLL loss over 8192 spans --------------------------------
__global__ __launch_bounds__(256) void k_loss(const float* __restrict__ logits,
                                              const int* __restrict__ labels,
                                              float* __restrict__ out_loss){
  __shared__ float red[256];
  float acc = 0.f;
  for (int i = threadIdx.x; i < BB*MAXW; i += 256){
    float z0 = logits[i*2], z1 = logits[i*2 + 1];
    float m = fmaxf(z0, z1);
    float lse = m + __logf(__expf(z0 - m) + __expf(z1 - m));
    float zl = labels[i] ? z1 : z0;
    acc += (lse - zl);
  }
  red[threadIdx.x] = acc;
  __syncthreads();
  for (int s2 = 128; s2; s2 >>= 1){
    if (threadIdx.x < s2) red[threadIdx.x] += red[threadIdx.x + s2];
    __syncthreads();
  }
  if (threadIdx.x == 0) out_loss[0] = red[0] / (float)(BB*MAXW);
}

extern "C" void kernel_launch(void* const* d_in, const int* in_sizes, int n_in,
                              void* d_out, int out_size, void* d_ws, size_t ws_size,
                              hipStream_t stream){
  (void)in_sizes; (void)n_in; (void)out_size;
  const int*   x      = (const int*)  d_in[0];
  const int*   labels = (const int*)  d_in[1];
  const int*   twid   = (const int*)  d_in[2];
  const float* emb    = (const float*)d_in[3];
  const float* Wih    = (const float*)d_in[4];
  const float* Whh    = (const float*)d_in[5];
  const float* bih    = (const float*)d_in[6];
  const float* bhh    = (const float*)d_in[7];
  const float* Wout   = (const float*)d_in[8];
  const float* bout   = (const float*)d_in[9];
  float* out = (float*)d_out;

  char* ws = (char*)d_ws;
  size_t off = 0;
  u16*   h_io   = (u16*)  (ws + off); off += (size_t)BB*SS*DD*2;   // 32 MB
  u16*   h_seq1 = (u16*)  (ws + off); off += (size_t)BB*SS*DD*2;   // 32 MB
  u16*   h_seq2 = (u16*)  (ws + off); off += (size_t)BB*SS*DD*2;   // 32 MB
  __half* xp    = (__half*)(ws + off); off += (size_t)BB*SS*G4*2;  // 128 MB
  u16*   Wih_b  = (u16*)  (ws + off); off += (size_t)2*G4*DD*2;    // 4 MB
  u16*   Whh_b  = (u16*)  (ws + off); off += (size_t)2*G4*DD*2;    // 4 MB
  float* biasp  = (float*)(ws + off); off += (size_t)2*G4*4;
  u16*   hbuf   = (u16*)  (ws + off); off += (size_t)2*BB*DD*2;
  unsigned int* flags = (unsigned int*)(ws + off); off += 256*4;
  (void)ws_size; // requires ~233 MB of workspace

  k_prep<<<2048, 256, 0, stream>>>(Wih, Whh, bih, bhh, Wih_b, Whh_b, biasp);
  k_embed<<<BB*SS, 256, 0, stream>>>(x, emb, h_io);

  const u16* lin = h_io;
  u16* louts[2] = {h_seq1, h_seq2};
  for (int l = 0; l < 2; l++){
    k_xproj<<<dim3(16, 256), 256, 0, stream>>>(lin, Wih_b + (size_t)l*G4*DD,
                                               biasp + (size_t)l*G4, xp);
    hipMemsetAsync(flags, 0, 256*sizeof(unsigned int), stream);
    k_recur<<<256, 64, 0, stream>>>(xp, Whh_b + (size_t)l*G4*DD, hbuf, louts[l], flags);
    lin = louts[l];
  }

  k_pool<<<BB*MAXW, 64, 0, stream>>>(h_seq2, twid, Wout, bout, out);
  k_loss<<<1, 256, 0, stream>>>(out, labels, out + BB*MAXW*2);
}

// Round 3
// 12716.104 us; speedup vs baseline: 2.0205x; 1.0722x over previous
//
#include <hip/hip_runtime.h>
#include <hip/hip_fp16.h>

typedef unsigned short u16;
typedef unsigned int u32;
typedef unsigned long long u64;
typedef short s16x8 __attribute__((ext_vector_type(8)));
typedef float f32x4 __attribute__((ext_vector_type(4)));

#define BB   32
#define SS   1024
#define DD   512
#define G4   2048
#define MAXW 256

__device__ __forceinline__ u16 f2bf(float f){
  unsigned int u = __float_as_uint(f);
  u += 0x7fff + ((u >> 16) & 1);           // RNE
  return (u16)(u >> 16);
}
__device__ __forceinline__ float bf2f(u16 h){
  return __uint_as_float(((unsigned int)h) << 16);
}
__device__ __forceinline__ float sigm(float x){ return 1.f/(1.f + __expf(-x)); }
__device__ __forceinline__ float ftanh(float x){
  float ax = fabsf(x);
  float e = __expf(-2.f*ax);               // in (0,1], never overflows
  float t = (1.f - e)/(1.f + e);
  return copysignf(t, x);
}

// ---------------- prep: fp32 weights -> bf16; fused permuted bias ----------
// bias_perm[l][n] = b_ih[l][g]+b_hh[l][g], g = (n&3)*512 + (n>>2)  (gate-minor)
__global__ void k_prep(const float* __restrict__ Wih, const float* __restrict__ Whh,
                       const float* __restrict__ bih, const float* __restrict__ bhh,
                       u16* __restrict__ Wih_b, u16* __restrict__ Whh_b,
                       float* __restrict__ biasp){
  long i = (long)blockIdx.x*blockDim.x + threadIdx.x;
  long n = 2l*G4*DD;
  long stride = (long)gridDim.x*blockDim.x;
  for (long k = i; k < n; k += stride){
    Wih_b[k] = f2bf(Wih[k]);
    Whh_b[k] = f2bf(Whh[k]);
  }
  for (long k = i; k < 2*G4; k += stride){
    int lyr = (int)(k / G4), nn = (int)(k % G4);
    int col = nn >> 2, q = nn & 3;
    int g = q*DD + col;
    biasp[k] = bih[lyr*G4 + g] + bhh[lyr*G4 + g];
  }
}

// ---------------- embedding gather -> bf16 [B*S][D] ------------------------
__global__ void k_embed(const int* __restrict__ x, const float* __restrict__ emb,
                        u16* __restrict__ out){
  int bs = blockIdx.x;                     // 0..32767
  int tok = x[bs];
  const float* src = emb + (size_t)tok * DD;
  u16* dst = out + (size_t)bs * DD;
  for (int d = threadIdx.x; d < DD; d += blockDim.x) dst[d] = f2bf(src[d]);
}

// ---------------- x-projection GEMM (layer 1 only) ------------------------
// A[M=32768][512] bf16 (tokens), Bw = W_ih layer0 [2048][512] bf16.
// Output xp[m][n] fp16, n in GATE-MINOR permuted order n = col*4+q.
// Includes bias. 128x128 tile, BK=64, 4 waves, XOR-swizzled LDS.
#define Bb_M 128
#define Bb_N 128
#define Bb_K 64
__global__ __launch_bounds__(256) void k_xproj(const u16* __restrict__ A,
                                               const u16* __restrict__ Bw,
                                               const float* __restrict__ biasp,
                                               __half* __restrict__ xp){
  __shared__ u16 As[Bb_M*Bb_K];
  __shared__ u16 Bs[Bb_N*Bb_K];
  const int tid = threadIdx.x;
  const int lane = tid & 63, wv = tid >> 6;
  const int bn = blockIdx.x;               // 0..15
  const int bm = blockIdx.y;               // 0..255
  const int m0 = bm * Bb_M, n0 = bn * Bb_N;
  const int wm = wv >> 1, wn = wv & 1;     // 2x2 waves of 64x64
  f32x4 acc[4][4] = {};

  for (int k0 = 0; k0 < DD; k0 += Bb_K){
    #pragma unroll
    for (int i = 0; i < 4; i++){
      int sg = tid + 256*i;                // 0..1023 : 128 rows x 8 segs(16B)
      int r = sg >> 3, c = sg & 7;
      int slot = c ^ (r & 7);
      const u16* gpa = A + (size_t)(m0 + r)*DD + k0 + c*8;
      *(int4*)((char*)As + r*128 + slot*16) = *(const int4*)gpa;
      int rn = n0 + r;
      int col = rn >> 2, q = rn & 3;
      const u16* gpb = Bw + (size_t)(q*DD + col)*DD + k0 + c*8;
      *(int4*)((char*)Bs + r*128 + slot*16) = *(const int4*)gpb;
    }
    __syncthreads();
    #pragma unroll
    for (int kk = 0; kk < 2; kk++){
      s16x8 af[4], bfr[4];
      #pragma unroll
      for (int fm = 0; fm < 4; fm++){
        int row = wm*64 + fm*16 + (lane & 15);
        int byt = row*128 + ((kk*64 + (lane>>4)*16) ^ ((row & 7) << 4));
        af[fm] = *(const s16x8*)((const char*)As + byt);
      }
      #pragma unroll
      for (int fn = 0; fn < 4; fn++){
        int row = wn*64 + fn*16 + (lane & 15);
        int byt = row*128 + ((kk*64 + (lane>>4)*16) ^ ((row & 7) << 4));
        bfr[fn] = *(const s16x8*)((const char*)Bs + byt);
      }
      #pragma unroll
      for (int fm = 0; fm < 4; fm++)
        #pragma unroll
        for (int fn = 0; fn < 4; fn++)
          acc[fm][fn] = __builtin_amdgcn_mfma_f32_16x16x32_bf16(af[fm], bfr[fn], acc[fm][fn], 0, 0, 0);
    }
    __syncthreads();
  }
  #pragma unroll
  for (int fn = 0; fn < 4; fn++){
    int n = n0 + wn*64 + fn*16 + (lane & 15);
    float badd = biasp[n];
    #pragma unroll
    for (int fm = 0; fm < 4; fm++){
      #pragma unroll
      for (int r = 0; r < 4; r++){
        int m = m0 + wm*64 + fm*16 + (lane>>4)*4 + r;
        xp[(size_t)m*G4 + n] = __float2half(acc[fm][fn][r] + badd);
      }
    }
  }
}

// ---------------- tagged h read: poll data words until tag matches --------
// slab: [batch][col] of 4B words {low16 = bf16 h, high16 = step tag}.
// Lane needs cols kk*32 + cc4*8 + 0..7 for kk=0..15 at row myb.
// 4 groups of 4 chunks; per-group retry (reloads are idempotent).
__device__ __forceinline__ void read_h(const u32* slab, int myb, int cc4,
                                       u32 tag, s16x8* bfr){
  const u64* row = (const u64*)(slab + (size_t)myb*512);
  #pragma unroll
  for (int g = 0; g < 4; g++){
    u64 qd[4][4];
    while (true){
      #pragma unroll
      for (int c2 = 0; c2 < 4; c2++){
        int kk = g*4 + c2;
        const u64* p = row + kk*16 + cc4*4;
        #pragma unroll
        for (int j = 0; j < 4; j++)
          qd[c2][j] = __hip_atomic_load((u64*)(p + j), __ATOMIC_RELAXED,
                                        __HIP_MEMORY_SCOPE_AGENT);
      }
      int ok = 1;
      #pragma unroll
      for (int c2 = 0; c2 < 4; c2++)
        #pragma unroll
        for (int j = 0; j < 4; j++){
          ok &= (int)(((u32)qd[c2][j]) >> 16) == (int)tag;
          ok &= (int)(((u32)(qd[c2][j] >> 32)) >> 16) == (int)tag;
        }
      if (__all(ok)) break;
      __builtin_amdgcn_s_sleep(1);         // back off while writers finish
    }
    #pragma unroll
    for (int c2 = 0; c2 < 4; c2++){
      union { s16x8 v; u32 u[4]; } r;
      #pragma unroll
      for (int j = 0; j < 4; j++){
        u32 lo = (u32)qd[c2][j] & 0xffffu;
        u32 hi = ((u32)(qd[c2][j] >> 32)) << 16;
        r.u[j] = lo | hi;
      }
      bfr[g*4 + c2] = r.v;
    }
  }
}

// ---------------- fused 2-layer persistent LSTM recurrence ----------------
// 512 WGs x 64 threads. WGs 0..255: layer 1; 256..511: layer 2 (pipelined,
// lags layer 1 by its poll on h1_t; computes W_ih2@h1_t on the fly).
// Sync is tag-in-data only: h words are {bf16|tag} stored with relaxed
// agent-scope atomics; readers poll the words themselves (2-leg chain).
// h1: full tagged sequence buffer [t][b][col] (readers may lag arbitrarily;
//     layer 1 never waits on layer 2 -> deadlock-free by construction).
// h2: 2-slot tagged buffer (writer provably <=2 steps ahead of any reader).
__global__ __launch_bounds__(64) void k_recur2(const __half* __restrict__ xp,
                                               const u16* __restrict__ Wih_b,
                                               const u16* __restrict__ Whh_b,
                                               const float* __restrict__ biasp,
                                               u32* __restrict__ h1t,
                                               u32* __restrict__ h2b,
                                               u16* __restrict__ h_seq2){
  const int lane = threadIdx.x;
  const int wg = blockIdx.x;
  const bool isL2 = wg >= 256;
  const int id = isL2 ? wg - 256 : wg;
  const int grp = id >> 7;                 // batch half
  const int w = id & 127;                  // col quad
  const int bb = grp*16, col0 = w*4;
  const int b_l = lane & 15, cc4 = lane >> 4;
  const int myb = bb + b_l;                // lane's batch row (C col)
  const int mycol = col0 + cc4;            // lane's h column
  // A-fragment addressing: A row sr = lane&15 = cc*4+q  <->  W row q*512+col0+cc
  const int cc = b_l >> 2, q = b_l & 3;
  const size_t arow = (size_t)(q*DD + col0 + cc)*DD;
  const int koff = cc4*8;

  const size_t lyrOff = isL2 ? (size_t)G4*DD : 0;
  s16x8 ahh[16];
  #pragma unroll
  for (int kk = 0; kk < 16; kk++)
    ahh[kk] = *(const s16x8*)(Whh_b + lyrOff + arow + kk*32 + koff);

  if (!isL2){
    // ---------------- layer 1 ----------------
    float c_state = 0.f;
    uint2 xv = *(const uint2*)(xp + ((size_t)myb*SS + 0)*G4 + mycol*4);
    for (int t = 0; t < SS; t++){
      f32x4 e0 = {0.f,0.f,0.f,0.f}, e1 = {0.f,0.f,0.f,0.f};
      if (t > 0){
        s16x8 bfr[16];
        read_h(h1t + (size_t)(t-1)*(BB*DD), myb, cc4, (u32)t, bfr);
        #pragma unroll
        for (int kk = 0; kk < 16; kk += 2){
          e0 = __builtin_amdgcn_mfma_f32_16x16x32_bf16(ahh[kk],   bfr[kk],   e0, 0, 0, 0);
          e1 = __builtin_amdgcn_mfma_f32_16x16x32_bf16(ahh[kk+1], bfr[kk+1], e1, 0, 0, 0);
        }
      }
      const __half* xq = (const __half*)&xv;
      float ig = sigm (e0[0] + e1[0] + __half2float(xq[0]));
      float fg = sigm (e0[1] + e1[1] + __half2float(xq[1]));
      float gg = ftanh(e0[2] + e1[2] + __half2float(xq[2]));
      float og = sigm (e0[3] + e1[3] + __half2float(xq[3]));
      c_state = fg*c_state + ig*gg;
      float h = og * ftanh(c_state);
      u32 word = (u32)f2bf(h) | ((u32)(t+1) << 16);
      __hip_atomic_store(h1t + (size_t)t*(BB*DD) + (size_t)myb*DD + mycol,
                         word, __ATOMIC_RELAXED, __HIP_MEMORY_SCOPE_AGENT);
      if (t + 1 < SS)
        xv = *(const uint2*)(xp + ((size_t)myb*SS + (t+1))*G4 + mycol*4);
    }
  } else {
    // ---------------- layer 2 (pipelined consumer) ----------------
    s16x8 aih[16];
    #pragma unroll
    for (int kk = 0; kk < 16; kk++)
      aih[kk] = *(const s16x8*)(Wih_b + lyrOff + arow + kk*32 + koff);
    const f32x4 b4 = *(const f32x4*)(biasp + G4 + mycol*4);
    float c_state = 0.f;
    for (int t = 0; t < SS; t++){
      f32x4 e0 = {0.f,0.f,0.f,0.f}, e1 = {0.f,0.f,0.f,0.f};
      s16x8 bfr[16];
      if (t > 0){
        // own recurrent input first (usually already fresh)
        read_h(h2b + (size_t)((t-1)&1)*(BB*DD), myb, cc4, (u32)t, bfr);
        #pragma unroll
        for (int kk = 0; kk < 16; kk += 2){
          e0 = __builtin_amdgcn_mfma_f32_16x16x32_bf16(ahh[kk],   bfr[kk],   e0, 0, 0, 0);
          e1 = __builtin_amdgcn_mfma_f32_16x16x32_bf16(ahh[kk+1], bfr[kk+1], e1, 0, 0, 0);
        }
      }
      // layer-1 output at this step (the pipeline gate)
      read_h(h1t + (size_t)t*(BB*DD), myb, cc4, (u32)(t+1), bfr);
      #pragma unroll
      for (int kk = 0; kk < 16; kk += 2){
        e0 = __builtin_amdgcn_mfma_f32_16x16x32_bf16(aih[kk],   bfr[kk],   e0, 0, 0, 0);
        e1 = __builtin_amdgcn_mfma_f32_16x16x32_bf16(aih[kk+1], bfr[kk+1], e1, 0, 0, 0);
      }
      float ig = sigm (e0[0] + e1[0] + b4[0]);
      float fg = sigm (e0[1] + e1[1] + b4[1]);
      float gg = ftanh(e0[2] + e1[2] + b4[2]);
      float og = sigm (e0[3] + e1[3] + b4[3]);
      c_state = fg*c_state + ig*gg;
      float h = og * ftanh(c_state);
      u16 h16 = f2bf(h);
      u32 word = (u32)h16 | ((u32)(t+1) << 16);
      __hip_atomic_store(h2b + (size_t)(t&1)*(BB*DD) + (size_t)myb*DD + mycol,
                         word, __ATOMIC_RELAXED, __HIP_MEMORY_SCOPE_AGENT);
      h_seq2[((size_t)myb*SS + t)*DD + mycol] = h16;   // plain store for pool
    }
  }
}

// ---------------- ragged mean-pool + span head ----------------------------
__global__ __launch_bounds__(64) void k_pool(const u16* __restrict__ h_seq,
                                             const int* __restrict__ twid,
                                             const float* __restrict__ Wout,
                                             const float* __restrict__ bout,
                                             float* __restrict__ out){
  int bw = blockIdx.x;                     // 0..8191
  int b = bw >> 8, w = bw & 255;
  const int* tw = twid + b*SS;
  __shared__ int s_lo, s_hi;
  if (threadIdx.x == 0){
    int l = 0, r = SS;
    while (l < r){ int m = (l + r) >> 1; if (tw[m] < w) l = m + 1; else r = m; }
    s_lo = l;
    r = SS;
    while (l < r){ int m = (l + r) >> 1; if (tw[m] < w + 1) l = m + 1; else r = m; }
    s_hi = l;
  }
  __syncthreads();
  int lo = s_lo, hi = s_hi, cnt = hi - lo;
  int lane = threadIdx.x;
  float p0 = 0.f, p1 = 0.f;
  if (cnt > 0){
    float sum[8] = {0.f,0.f,0.f,0.f,0.f,0.f,0.f,0.f};
    for (int t = lo; t < hi; t++){
      const u16* hp = h_seq + ((size_t)b*SS + t)*DD + lane*8;
      int4 v = *(const int4*)hp;
      const u16* u = (const u16*)&v;
      #pragma unroll
      for (int j = 0; j < 8; j++) sum[j] += bf2f(u[j]);
    }
    float inv = 1.f/(float)cnt;
    #pragma unroll
    for (int j = 0; j < 8; j++){
      float pv = sum[j]*inv;
      int d = lane*8 + j;
      p0 += pv * Wout[d];
      p1 += pv * Wout[DD + d];
    }
  }
  #pragma unroll
  for (int off = 32; off; off >>= 1){
    p0 += __shfl_down(p0, off);
    p1 += __shfl_down(p1, off);
  }
  if (lane == 0){
    out[bw*2 + 0] = p0 + bout[0];
    out[bw*2 + 1] = p1 + bout[1];
  }
}

// ---------------- NLL loss over 8192 spans --------------------------------
__global__ __launch_bounds__(256) void k_loss(const float* __restrict__ logits,
                                              const int* __restrict__ labels,
                                              float* __restrict__ out_loss){
  __shared__ float red[256];
  float acc = 0.f;
  for (int i = threadIdx.x; i < BB*MAXW; i += 256){
    float z0 = logits[i*2], z1 = logits[i*2 + 1];
    float m = fmaxf(z0, z1);
    float lse = m + __logf(__expf(z0 - m) + __expf(z1 - m));
    float zl = labels[i] ? z1 : z0;
    acc += (lse - zl);
  }
  red[threadIdx.x] = acc;
  __syncthreads();
  for (int s2 = 128; s2; s2 >>= 1){
    if (threadIdx.x < s2) red[threadIdx.x] += red[threadIdx.x + s2];
    __syncthreads();
  }
  if (threadIdx.x == 0) out_loss[0] = red[0] / (float)(BB*MAXW);
}

extern "C" void kernel_launch(void* const* d_in, const int* in_sizes, int n_in,
                              void* d_out, int out_size, void* d_ws, size_t ws_size,
                              hipStream_t stream){
  (void)in_sizes; (void)n_in; (void)out_size; (void)ws_size;
  const int*   x      = (const int*)  d_in[0];
  const int*   labels = (const int*)  d_in[1];
  const int*   twid   = (const int*)  d_in[2];
  const float* emb    = (const float*)d_in[3];
  const float* Wih    = (const float*)d_in[4];
  const float* Whh    = (const float*)d_in[5];
  const float* bih    = (const float*)d_in[6];
  const float* bhh    = (const float*)d_in[7];
  const float* Wout   = (const float*)d_in[8];
  const float* bout   = (const float*)d_in[9];
  float* out = (float*)d_out;

  char* ws = (char*)d_ws;
  size_t off = 0;
  // region A (64MB): h1 tagged sequence; first 32MB doubles as embed output
  u32*   h1t    = (u32*)  (ws + off);
  u16*   h_io   = (u16*)  (ws + off); off += (size_t)SS*BB*DD*4;   // 64 MB
  __half* xp    = (__half*)(ws + off); off += (size_t)BB*SS*G4*2;  // 128 MB
  u16*   h_seq2 = (u16*)  (ws + off); off += (size_t)BB*SS*DD*2;   // 32 MB
  u16*   Wih_b  = (u16*)  (ws + off); off += (size_t)2*G4*DD*2;    // 4 MB
  u16*   Whh_b  = (u16*)  (ws + off); off += (size_t)2*G4*DD*2;    // 4 MB
  float* biasp  = (float*)(ws + off); off += (size_t)2*G4*4;
  u32*   h2b    = (u32*)  (ws + off); off += (size_t)2*BB*DD*4;    // 128 KB
  // total ~232.1 MB (< proven 233 MB budget)

  k_prep<<<2048, 256, 0, stream>>>(Wih, Whh, bih, bhh, Wih_b, Whh_b, biasp);
  k_embed<<<BB*SS, 256, 0, stream>>>(x, emb, h_io);
  k_xproj<<<dim3(16, 256), 256, 0, stream>>>(h_io, Wih_b, biasp, xp);

  // clear tag buffers (h_io is dead after k_xproj; stream-ordered)
  hipMemsetAsync(h1t, 0, (size_t)SS*BB*DD*4, stream);
  hipMemsetAsync(h2b, 0, (size_t)2*BB*DD*4, stream);

  k_recur2<<<512, 64, 0, stream>>>(xp, Wih_b, Whh_b, biasp, h1t, h2b, h_seq2);

  k_pool<<<BB*MAXW, 64, 0, stream>>>(h_seq2, twid, Wout, bout, out);
  k_loss<<<1, 256, 0, stream>>>(out, labels, out + BB*MAXW*2);
}

// Round 4
// 10418.637 us; speedup vs baseline: 2.4661x; 1.2205x over previous
//
#include <hip/hip_runtime.h>
#include <hip/hip_fp16.h>

typedef unsigned short u16;
typedef unsigned int u32;
typedef unsigned long long u64;
typedef short s16x8 __attribute__((ext_vector_type(8)));
typedef float f32x4 __attribute__((ext_vector_type(4)));

#define BB   32
#define SS   1024
#define DD   512
#define G4   2048
#define MAXW 256
#define NWG  32      // workgroups per layer
#define RING 8       // h1 ring slots (backpressure window)

__device__ __forceinline__ u16 f2bf(float f){
  unsigned int u = __float_as_uint(f);
  u += 0x7fff + ((u >> 16) & 1);           // RNE
  return (u16)(u >> 16);
}
__device__ __forceinline__ float bf2f(u16 h){
  return __uint_as_float(((unsigned int)h) << 16);
}
__device__ __forceinline__ float sigm(float x){ return 1.f/(1.f + __expf(-x)); }
__device__ __forceinline__ float ftanh(float x){
  float ax = fabsf(x);
  float e = __expf(-2.f*ax);               // in (0,1], never overflows
  float t = (1.f - e)/(1.f + e);
  return copysignf(t, x);
}

// ---------------- prep: fp32 weights -> bf16; fused permuted bias ----------
// bias_perm[l][n] = b_ih[l][g]+b_hh[l][g], g = (n&3)*512 + (n>>2)  (gate-minor)
__global__ void k_prep(const float* __restrict__ Wih, const float* __restrict__ Whh,
                       const float* __restrict__ bih, const float* __restrict__ bhh,
                       u16* __restrict__ Wih_b, u16* __restrict__ Whh_b,
                       float* __restrict__ biasp){
  long i = (long)blockIdx.x*blockDim.x + threadIdx.x;
  long n = 2l*G4*DD;
  long stride = (long)gridDim.x*blockDim.x;
  for (long k = i; k < n; k += stride){
    Wih_b[k] = f2bf(Wih[k]);
    Whh_b[k] = f2bf(Whh[k]);
  }
  for (long k = i; k < 2*G4; k += stride){
    int lyr = (int)(k / G4), nn = (int)(k % G4);
    int col = nn >> 2, q = nn & 3;
    int g = q*DD + col;
    biasp[k] = bih[lyr*G4 + g] + bhh[lyr*G4 + g];
  }
}

// ---------------- embedding gather -> bf16 [B*S][D] ------------------------
__global__ void k_embed(const int* __restrict__ x, const float* __restrict__ emb,
                        u16* __restrict__ out){
  int bs = blockIdx.x;                     // 0..32767
  int tok = x[bs];
  const float* src = emb + (size_t)tok * DD;
  u16* dst = out + (size_t)bs * DD;
  for (int d = threadIdx.x; d < DD; d += blockDim.x) dst[d] = f2bf(src[d]);
}

// ---------------- x-projection GEMM (layer 1 only) ------------------------
#define Bb_M 128
#define Bb_N 128
#define Bb_K 64
__global__ __launch_bounds__(256) void k_xproj(const u16* __restrict__ A,
                                               const u16* __restrict__ Bw,
                                               const float* __restrict__ biasp,
                                               __half* __restrict__ xp){
  __shared__ u16 As[Bb_M*Bb_K];
  __shared__ u16 Bs[Bb_N*Bb_K];
  const int tid = threadIdx.x;
  const int lane = tid & 63, wv = tid >> 6;
  const int bn = blockIdx.x;               // 0..15
  const int bm = blockIdx.y;               // 0..255
  const int m0 = bm * Bb_M, n0 = bn * Bb_N;
  const int wm = wv >> 1, wn = wv & 1;     // 2x2 waves of 64x64
  f32x4 acc[4][4] = {};

  for (int k0 = 0; k0 < DD; k0 += Bb_K){
    #pragma unroll
    for (int i = 0; i < 4; i++){
      int sg = tid + 256*i;                // 0..1023 : 128 rows x 8 segs(16B)
      int r = sg >> 3, c = sg & 7;
      int slot = c ^ (r & 7);
      const u16* gpa = A + (size_t)(m0 + r)*DD + k0 + c*8;
      *(int4*)((char*)As + r*128 + slot*16) = *(const int4*)gpa;
      int rn = n0 + r;
      int col = rn >> 2, q = rn & 3;
      const u16* gpb = Bw + (size_t)(q*DD + col)*DD + k0 + c*8;
      *(int4*)((char*)Bs + r*128 + slot*16) = *(const int4*)gpb;
    }
    __syncthreads();
    #pragma unroll
    for (int kk = 0; kk < 2; kk++){
      s16x8 af[4], bfr[4];
      #pragma unroll
      for (int fm = 0; fm < 4; fm++){
        int row = wm*64 + fm*16 + (lane & 15);
        int byt = row*128 + ((kk*64 + (lane>>4)*16) ^ ((row & 7) << 4));
        af[fm] = *(const s16x8*)((const char*)As + byt);
      }
      #pragma unroll
      for (int fn = 0; fn < 4; fn++){
        int row = wn*64 + fn*16 + (lane & 15);
        int byt = row*128 + ((kk*64 + (lane>>4)*16) ^ ((row & 7) << 4));
        bfr[fn] = *(const s16x8*)((const char*)Bs + byt);
      }
      #pragma unroll
      for (int fm = 0; fm < 4; fm++)
        #pragma unroll
        for (int fn = 0; fn < 4; fn++)
          acc[fm][fn] = __builtin_amdgcn_mfma_f32_16x16x32_bf16(af[fm], bfr[fn], acc[fm][fn], 0, 0, 0);
    }
    __syncthreads();
  }
  #pragma unroll
  for (int fn = 0; fn < 4; fn++){
    int n = n0 + wn*64 + fn*16 + (lane & 15);
    float badd = biasp[n];
    #pragma unroll
    for (int fm = 0; fm < 4; fm++){
      #pragma unroll
      for (int r = 0; r < 4; r++){
        int m = m0 + wm*64 + fm*16 + (lane>>4)*4 + r;
        xp[(size_t)m*G4 + n] = __float2half(acc[fm][fn][r] + badd);
      }
    }
  }
}

// ---------------- bulk h load: global (agent atomic, L2-bypass) -> LDS ----
// slab: [32 batch][512 col] bf16 (64KB). 256 threads x 16 x 8B loads.
// LDS layout: row b (1KB) with 16B-granule XOR swizzle ((b&7)<<4).
__device__ __forceinline__ void load_h(const u16* slab, char* lds, int tid){
  const u64* s64 = (const u64*)slab;
  #pragma unroll
  for (int j = 0; j < 16; j++){
    int e = j*256 + tid;                   // 8B unit index, 0..4095
    u64 d = __hip_atomic_load(s64 + e, __ATOMIC_RELAXED, __HIP_MEMORY_SCOPE_AGENT);
    int b = e >> 7, c8 = e & 127;
    *(u64*)(lds + b*1024 + ((c8*8) ^ ((b & 7) << 4))) = d;
  }
}

// ---------------- fused 2-layer persistent LSTM recurrence ----------------
// 64 WGs x 256 threads. WGs 0..31: layer 1; 32..63: layer 2 (pipelined).
// WG id owns permuted gate-rows [64id,64id+64) = h-cols [16id,16id+16),
// all 32 batches. Weights live in registers (A-frags). Sync protocol:
//   writer: packed-4B agent-atomic h stores -> vmcnt(0) -> per-wave done ->
//           __syncthreads -> tid0 stores 4B sentinel (sent[layer*32+id]=t+1)
//   reader: polls the 64-word sentinel array (one 4B load/lane), then
//           bulk-reads h exactly once into LDS (load_h), ds_read fragments.
// h1: 8-slot ring + backpressure (L1 waits l2prog >= t-7) -> no overwrite
//     before layer 2 consumes; dependency t strictly decreases => no deadlock.
// h2: 2-slot ring (writer at t+1 gated on all l2prog >= t+1).
__global__ __launch_bounds__(256) void k_recur2(const __half* __restrict__ xp,
                                                const u16* __restrict__ Wih_b,
                                                const u16* __restrict__ Whh_b,
                                                const float* __restrict__ biasp,
                                                u16* __restrict__ h1r,
                                                u16* __restrict__ h2r,
                                                u32* __restrict__ sent,
                                                u16* __restrict__ h_seq2){
  __shared__ char hA[32768];
  __shared__ char hB[32768];               // L2 only (h2 recurrent input)
  const int tid = threadIdx.x;
  const int lane = tid & 63, wv = tid >> 6;
  const int wg = blockIdx.x;
  const bool isL2 = wg >= NWG;
  const int id = isL2 ? wg - NWG : wg;

  // weight A-fragment: perm gate-row pa = id*64 + wv*16 + (lane&15)
  const int pa = id*64 + wv*16 + (lane & 15);
  const int wcol = pa >> 2, wq = pa & 3;
  const size_t arow = (size_t)(wq*DD + wcol)*DD;
  const int koff = (lane >> 4) * 8;
  // output ownership: C col = lane&15 = batch; lane's h-col:
  const int oc = id*16 + wv*4 + (lane >> 4);
  const int b0 = lane & 15, b1 = b0 + 16;

  const size_t lyrOff = isL2 ? (size_t)G4*DD : 0;
  s16x8 ahh[16];
  #pragma unroll
  for (int kk = 0; kk < 16; kk++)
    ahh[kk] = *(const s16x8*)(Whh_b + lyrOff + arow + kk*32 + koff);
  s16x8 aih[16];
  if (isL2){
    #pragma unroll
    for (int kk = 0; kk < 16; kk++)
      aih[kk] = *(const s16x8*)(Wih_b + lyrOff + arow + kk*32 + koff);
  }
  f32x4 b4 = {0.f,0.f,0.f,0.f};
  if (isL2) b4 = *(const f32x4*)(biasp + G4 + oc*4);

  float c0 = 0.f, c1 = 0.f;

  for (int t = 0; t < SS; t++){
    // xp prefetch (L1 only) — independent of sync, issues early
    uint2 xv0 = {0,0}, xv1 = {0,0};
    if (!isL2){
      xv0 = *(const uint2*)(xp + ((size_t)b0*SS + t)*G4 + oc*4);
      xv1 = *(const uint2*)(xp + ((size_t)b1*SS + t)*G4 + oc*4);
    }
    // sentinel poll: lanes<32 check own-layer-input; lanes>=32 the other cond
    u32 lo_need, hi_need;
    if (!isL2){ lo_need = (u32)t; hi_need = (t > 7) ? (u32)(t - 7) : 0u; }
    else      { lo_need = (u32)(t + 1); hi_need = (u32)t; }
    if (lo_need | hi_need){
      u32 need = (lane < 32) ? lo_need : hi_need;
      while (true){
        u32 v = __hip_atomic_load(&sent[lane], __ATOMIC_RELAXED,
                                  __HIP_MEMORY_SCOPE_AGENT);
        if (__all((int)(v >= need))) break;
        __builtin_amdgcn_s_sleep(1);
      }
    }
    // bulk-stage h into LDS (exactly once per step)
    if (!isL2){
      if (t > 0) load_h(h1r + (size_t)((t-1) & (RING-1))*(BB*DD), hA, tid);
    } else {
      load_h(h1r + (size_t)(t & (RING-1))*(BB*DD), hA, tid);
      if (t > 0) load_h(h2r + (size_t)((t-1) & 1)*(BB*DD), hB, tid);
    }
    __syncthreads();

    // MFMA phase
    f32x4 e0 = {0.f,0.f,0.f,0.f}, e1 = {0.f,0.f,0.f,0.f};
    if (t > 0){
      const char* src = isL2 ? hB : hA;    // recurrent input
      #pragma unroll
      for (int kk = 0; kk < 16; kk++){
        int byt = (lane & 15)*1024 + ((kk*64 + (lane>>4)*16) ^ (((lane & 15) & 7) << 4));
        s16x8 f0 = *(const s16x8*)(src + byt);
        s16x8 f1 = *(const s16x8*)(src + byt + 16*1024);
        e0 = __builtin_amdgcn_mfma_f32_16x16x32_bf16(ahh[kk], f0, e0, 0, 0, 0);
        e1 = __builtin_amdgcn_mfma_f32_16x16x32_bf16(ahh[kk], f1, e1, 0, 0, 0);
      }
    }
    if (isL2){
      #pragma unroll
      for (int kk = 0; kk < 16; kk++){
        int byt = (lane & 15)*1024 + ((kk*64 + (lane>>4)*16) ^ (((lane & 15) & 7) << 4));
        s16x8 f0 = *(const s16x8*)(hA + byt);
        s16x8 f1 = *(const s16x8*)(hA + byt + 16*1024);
        e0 = __builtin_amdgcn_mfma_f32_16x16x32_bf16(aih[kk], f0, e0, 0, 0, 0);
        e1 = __builtin_amdgcn_mfma_f32_16x16x32_bf16(aih[kk], f1, e1, 0, 0, 0);
      }
    }

    // gates: e[r] = gate q=r of col oc (r: i,f,g,o); e0->b0, e1->b1
    float x0, x1, x2, x3, y0, y1, y2, y3;
    if (!isL2){
      const __half* xq0 = (const __half*)&xv0;
      const __half* xq1 = (const __half*)&xv1;
      x0 = __half2float(xq0[0]); x1 = __half2float(xq0[1]);
      x2 = __half2float(xq0[2]); x3 = __half2float(xq0[3]);
      y0 = __half2float(xq1[0]); y1 = __half2float(xq1[1]);
      y2 = __half2float(xq1[2]); y3 = __half2float(xq1[3]);
    } else {
      x0 = b4[0]; x1 = b4[1]; x2 = b4[2]; x3 = b4[3];
      y0 = b4[0]; y1 = b4[1]; y2 = b4[2]; y3 = b4[3];
    }
    float ig = sigm (e0[0] + x0), fg = sigm (e0[1] + x1);
    float gg = ftanh(e0[2] + x2), og = sigm (e0[3] + x3);
    c0 = fg*c0 + ig*gg;
    float hv0 = og * ftanh(c0);
    ig = sigm (e1[0] + y0); fg = sigm (e1[1] + y1);
    gg = ftanh(e1[2] + y2); og = sigm (e1[3] + y3);
    c1 = fg*c1 + ig*gg;
    float hv1 = og * ftanh(c1);

    // store h: pack col pairs (lanes with even lane>>4 pack partner lane+16)
    u16 hh0 = f2bf(hv0), hh1 = f2bf(hv1);
    u32 p0 = (u32)hh0 | (((u32)__shfl((int)hh0, (lane + 16) & 63) & 0xffffu) << 16);
    u32 p1 = (u32)hh1 | (((u32)__shfl((int)hh1, (lane + 16) & 63) & 0xffffu) << 16);
    u16* dst = isL2 ? (h2r + (size_t)(t & 1)*(BB*DD))
                    : (h1r + (size_t)(t & (RING-1))*(BB*DD));
    if (((lane >> 4) & 1) == 0){
      __hip_atomic_store((u32*)(dst + (size_t)b0*DD + oc), p0,
                         __ATOMIC_RELAXED, __HIP_MEMORY_SCOPE_AGENT);
      __hip_atomic_store((u32*)(dst + (size_t)b1*DD + oc), p1,
                         __ATOMIC_RELAXED, __HIP_MEMORY_SCOPE_AGENT);
      if (isL2){
        *(u32*)(h_seq2 + ((size_t)b0*SS + t)*DD + oc) = p0;
        *(u32*)(h_seq2 + ((size_t)b1*SS + t)*DD + oc) = p1;
      }
    }
    asm volatile("s_waitcnt vmcnt(0)" ::: "memory");  // h stores at coherence pt
    __syncthreads();                                   // all waves drained + LDS free
    if (tid == 0)
      __hip_atomic_store(&sent[(isL2 ? NWG : 0) + id], (u32)(t + 1),
                         __ATOMIC_RELAXED, __HIP_MEMORY_SCOPE_AGENT);
  }
}

// ---------------- ragged mean-pool + span head ----------------------------
__global__ __launch_bounds__(64) void k_pool(const u16* __restrict__ h_seq,
                                             const int* __restrict__ twid,
                                             const float* __restrict__ Wout,
                                             const float* __restrict__ bout,
                                             float* __restrict__ out){
  int bw = blockIdx.x;                     // 0..8191
  int b = bw >> 8, w = bw & 255;
  const int* tw = twid + b*SS;
  __shared__ int s_lo, s_hi;
  if (threadIdx.x == 0){
    int l = 0, r = SS;
    while (l < r){ int m = (l + r) >> 1; if (tw[m] < w) l = m + 1; else r = m; }
    s_lo = l;
    r = SS;
    while (l < r){ int m = (l + r) >> 1; if (tw[m] < w + 1) l = m + 1; else r = m; }
    s_hi = l;
  }
  __syncthreads();
  int lo = s_lo, hi = s_hi, cnt = hi - lo;
  int lane = threadIdx.x;
  float p0 = 0.f, p1 = 0.f;
  if (cnt > 0){
    float sum[8] = {0.f,0.f,0.f,0.f,0.f,0.f,0.f,0.f};
    for (int t = lo; t < hi; t++){
      const u16* hp = h_seq + ((size_t)b*SS + t)*DD + lane*8;
      int4 v = *(const int4*)hp;
      const u16* u = (const u16*)&v;
      #pragma unroll
      for (int j = 0; j < 8; j++) sum[j] += bf2f(u[j]);
    }
    float inv = 1.f/(float)cnt;
    #pragma unroll
    for (int j = 0; j < 8; j++){
      float pv = sum[j]*inv;
      int d = lane*8 + j;
      p0 += pv * Wout[d];
      p1 += pv * Wout[DD + d];
    }
  }
  #pragma unroll
  for (int off = 32; off; off >>= 1){
    p0 += __shfl_down(p0, off);
    p1 += __shfl_down(p1, off);
  }
  if (lane == 0){
    out[bw*2 + 0] = p0 + bout[0];
    out[bw*2 + 1] = p1 + bout[1];
  }
}

// ---------------- NLL loss over 8192 spans --------------------------------
__global__ __launch_bounds__(256) void k_loss(const float* __restrict__ logits,
                                              const int* __restrict__ labels,
                                              float* __restrict__ out_loss){
  __shared__ float red[256];
  float acc = 0.f;
  for (int i = threadIdx.x; i < BB*MAXW; i += 256){
    float z0 = logits[i*2], z1 = logits[i*2 + 1];
    float m = fmaxf(z0, z1);
    float lse = m + __logf(__expf(z0 - m) + __expf(z1 - m));
    float zl = labels[i] ? z1 : z0;
    acc += (lse - zl);
  }
  red[threadIdx.x] = acc;
  __syncthreads();
  for (int s2 = 128; s2; s2 >>= 1){
    if (threadIdx.x < s2) red[threadIdx.x] += red[threadIdx.x + s2];
    __syncthreads();
  }
  if (threadIdx.x == 0) out_loss[0] = red[0] / (float)(BB*MAXW);
}

extern "C" void kernel_launch(void* const* d_in, const int* in_sizes, int n_in,
                              void* d_out, int out_size, void* d_ws, size_t ws_size,
                              hipStream_t stream){
  (void)in_sizes; (void)n_in; (void)out_size; (void)ws_size;
  const int*   x      = (const int*)  d_in[0];
  const int*   labels = (const int*)  d_in[1];
  const int*   twid   = (const int*)  d_in[2];
  const float* emb    = (const float*)d_in[3];
  const float* Wih    = (const float*)d_in[4];
  const float* Whh    = (const float*)d_in[5];
  const float* bih    = (const float*)d_in[6];
  const float* bhh    = (const float*)d_in[7];
  const float* Wout   = (const float*)d_in[8];
  const float* bout   = (const float*)d_in[9];
  float* out = (float*)d_out;

  char* ws = (char*)d_ws;
  size_t off = 0;
  u16*   h_io   = (u16*)  (ws + off); off += (size_t)BB*SS*DD*2;   // 32 MB
  __half* xp    = (__half*)(ws + off); off += (size_t)BB*SS*G4*2;  // 128 MB
  u16*   h_seq2 = (u16*)  (ws + off); off += (size_t)BB*SS*DD*2;   // 32 MB
  u16*   Wih_b  = (u16*)  (ws + off); off += (size_t)2*G4*DD*2;    // 4 MB
  u16*   Whh_b  = (u16*)  (ws + off); off += (size_t)2*G4*DD*2;    // 4 MB
  float* biasp  = (float*)(ws + off); off += (size_t)2*G4*4;       // 16 KB
  u16*   h1r    = (u16*)  (ws + off); off += (size_t)RING*BB*DD*2; // 256 KB
  u16*   h2r    = (u16*)  (ws + off); off += (size_t)2*BB*DD*2;    // 64 KB
  u32*   sent   = (u32*)  (ws + off); off += 64*4;
  // total ~200.3 MB

  k_prep<<<2048, 256, 0, stream>>>(Wih, Whh, bih, bhh, Wih_b, Whh_b, biasp);
  k_embed<<<BB*SS, 256, 0, stream>>>(x, emb, h_io);
  k_xproj<<<dim3(16, 256), 256, 0, stream>>>(h_io, Wih_b, biasp, xp);

  hipMemsetAsync(sent, 0, 64*sizeof(u32), stream);

  k_recur2<<<2*NWG, 256, 0, stream>>>(xp, Wih_b, Whh_b, biasp,
                                      h1r, h2r, sent, h_seq2);

  k_pool<<<BB*MAXW, 64, 0, stream>>>(h_seq2, twid, Wout, bout, out);
  k_loss<<<1, 256, 0, stream>>>(out, labels, out + BB*MAXW*2);
}

// Round 7
// 5522.742 us; speedup vs baseline: 4.6522x; 1.8865x over previous
//
#include <hip/hip_runtime.h>
#include <hip/hip_fp16.h>

typedef unsigned short u16;
typedef unsigned int u32;
typedef unsigned long long u64;
typedef short s16x8 __attribute__((ext_vector_type(8)));
typedef float f32x4 __attribute__((ext_vector_type(4)));

#define BB   32
#define SS   1024
#define DD   512
#define G4   2048
#define MAXW 256
#define NWG  32                 // workgroups per layer
#define RING 8                  // h1 ring slots (pipeline window)
#define HS   (BB*DD)            // u16 elements per h slab (32KB)

__device__ __forceinline__ u16 f2bf(float f){
  unsigned int u = __float_as_uint(f);
  u += 0x7fff + ((u >> 16) & 1);           // RNE
  return (u16)(u >> 16);
}
__device__ __forceinline__ float bf2f(u16 h){
  return __uint_as_float(((unsigned int)h) << 16);
}
__device__ __forceinline__ float sigm(float x){ return 1.f/(1.f + __expf(-x)); }
__device__ __forceinline__ float ftanh(float x){
  float ax = fabsf(x);
  float e = __expf(-2.f*ax);               // in (0,1], never overflows
  float t = (1.f - e)/(1.f + e);
  return copysignf(t, x);
}

// ---------------- prep: fp32 weights -> bf16; fused permuted bias ----------
// bias_perm[l][n] = b_ih[l][g]+b_hh[l][g], g = (n&3)*512 + (n>>2) (gate-minor)
__global__ void k_prep(const float* __restrict__ Wih, const float* __restrict__ Whh,
                       const float* __restrict__ bih, const float* __restrict__ bhh,
                       u16* __restrict__ Wih_b, u16* __restrict__ Whh_b,
                       float* __restrict__ biasp){
  long i = (long)blockIdx.x*blockDim.x + threadIdx.x;
  long n = 2l*G4*DD;
  long stride = (long)gridDim.x*blockDim.x;
  for (long k = i; k < n; k += stride){
    Wih_b[k] = f2bf(Wih[k]);
    Whh_b[k] = f2bf(Whh[k]);
  }
  for (long k = i; k < 2*G4; k += stride){
    int lyr = (int)(k / G4), nn = (int)(k % G4);
    int col = nn >> 2, q = nn & 3;
    int g = q*DD + col;
    biasp[k] = bih[lyr*G4 + g] + bhh[lyr*G4 + g];
  }
}

// ---------------- embedding gather -> bf16 [B*S][D] ------------------------
__global__ void k_embed(const int* __restrict__ x, const float* __restrict__ emb,
                        u16* __restrict__ out){
  int bs = blockIdx.x;
  int tok = x[bs];
  const float* src = emb + (size_t)tok * DD;
  u16* dst = out + (size_t)bs * DD;
  for (int d = threadIdx.x; d < DD; d += blockDim.x) dst[d] = f2bf(src[d]);
}

// ---- wait until all lanes see *p1>=n1 and *p2>=n2 (wave-uniform loads) ----
// budget is TOTAL across the kernel: a broken protocol fails loudly in ~1s
// with wrong output instead of hanging the harness.
__device__ __forceinline__ void wait2(const u32* p1, u32 n1,
                                      const u32* p2, u32 n2, int& budget){
  if (n1 == 0u && n2 == 0u) return;
  while (budget > 0){
    u32 v1 = n1 ? __hip_atomic_load(p1, __ATOMIC_RELAXED, __HIP_MEMORY_SCOPE_AGENT)
                : 0xffffffffu;
    u32 v2 = n2 ? __hip_atomic_load(p2, __ATOMIC_RELAXED, __HIP_MEMORY_SCOPE_AGENT)
                : 0xffffffffu;
    int ok = (v1 >= n1) && (v2 >= n2);
    if (__all(ok)) break;
    budget--;
    __builtin_amdgcn_s_sleep(1);
  }
}

// ---- stage a 32x512 bf16 slab (32KB) into XOR-swizzled LDS ---------------
// 256 threads x 16 x 8B agent-atomic loads (MALL-coherent, R2/R4-proven).
__device__ __forceinline__ void stage_h(const u16* slab, char* lds, int tid){
  u64 d[16];
  #pragma unroll
  for (int j = 0; j < 16; j++)
    d[j] = __hip_atomic_load((const u64*)slab + j*256 + tid,
                             __ATOMIC_RELAXED, __HIP_MEMORY_SCOPE_AGENT);
  #pragma unroll
  for (int j = 0; j < 16; j++){
    int e = j*256 + tid;
    int b = e >> 7, c8 = e & 127;
    *(u64*)(lds + b*1024 + ((c8*8) ^ ((b & 7) << 4))) = d[j];
  }
}

// ---------------- fused 2-layer persistent LSTM recurrence ----------------
// 64 WGs x 256 threads, all co-resident by construction (64 < 256 CUs).
// WGs 0..31: layer 1 (computes W_ih1@x_t on the fly from h_io); 32..63:
// layer 2 (pipelined one step behind, W_ih2@h1_t on the fly).
// WG id owns permuted gate-rows [64id,64id+64) = h-cols [16id,16id+16),
// all 32 batches; weights register-resident (launch_bounds(256,1)).
// Sync: ONE monotonic counter per layer (c1,c2). Publish = h stores ->
// vmcnt(0) -> __syncthreads -> tid0 atomicAdd(+1). Wait = wave-uniform
// polls of the two counter words (2 coalesced requests/wave/iter — kills
// the flag-array fan-in that dominated R2/R4).
// h1: 8-slot ring; L1 backpressure c2 >= 32*(t-7). h2: 2-slot ring; safe
// because step t+2 waits all-L2-finished step t+1 (reads precede publish).
__global__ __launch_bounds__(256, 1) void k_recur2(
    const u16* __restrict__ h_io,
    const u16* __restrict__ Wih_b,
    const u16* __restrict__ Whh_b,
    const float* __restrict__ biasp,
    u16* __restrict__ h1r,
    u16* __restrict__ h2r,
    u32* __restrict__ flags,
    u16* __restrict__ h_seq2){
  __shared__ char hX[32768];               // L1: x tile   | L2: h1 tile
  __shared__ char hH[32768];               // L1: h1 tile  | L2: h2 tile
  const int tid = threadIdx.x;
  const int lane = tid & 63, wv = tid >> 6;
  const int wg = blockIdx.x;
  const bool isL2 = wg >= NWG;
  const int id = wg & (NWG - 1);

  u32* c1 = flags;                         // layer-1 progress (own 128B line)
  u32* c2 = flags + 64;                    // layer-2 progress

  // weight A-fragments: perm gate-row pa = id*64 + wv*16 + (lane&15)
  const int pa = id*64 + wv*16 + (lane & 15);
  const size_t arow = (size_t)((pa & 3)*DD + (pa >> 2))*DD;
  const int koff = (lane >> 4)*8;
  const size_t lyrOff = isL2 ? (size_t)G4*DD : 0;
  s16x8 ahh[16], aih[16];
  #pragma unroll
  for (int kk = 0; kk < 16; kk++){
    ahh[kk] = *(const s16x8*)(Whh_b + lyrOff + arow + kk*32 + koff);
    aih[kk] = *(const s16x8*)(Wih_b + lyrOff + arow + kk*32 + koff);
  }
  const int oc = id*16 + wv*4 + (lane >> 4);      // lane's h column
  const int b0 = lane & 15, b1 = b0 + 16;         // lane's two batches
  const f32x4 b4 = *(const f32x4*)(biasp + (isL2 ? G4 : 0) + oc*4);
  float c0 = 0.f, cst1 = 0.f;
  int budget = 1 << 22;                    // total spin budget (anti-hang)

  for (int t = 0; t < SS; t++){
    u64 xd[16];
    if (!isL2){
      // x_t tile: rows are 1KB lines at stride S*D; plain loads (read-only,
      // L3-resident). Issued BEFORE the poll so latency hides under it.
      #pragma unroll
      for (int j = 0; j < 16; j++){
        int e = j*256 + tid;
        xd[j] = *((const u64*)h_io + ((size_t)(e >> 7)*SS + t)*128 + (e & 127));
      }
      // wait own-layer prev step; backpressure on L2 being within 7 steps
      u32 n1 = (t > 0) ? (u32)(NWG*t) : 0u;
      u32 n2 = (t >= RING) ? (u32)(NWG*(t - RING + 1)) : 0u;
      wait2(c1, n1, c2, n2, budget);
      if (t > 0) stage_h(h1r + (size_t)((t-1) & (RING-1))*HS, hH, tid);
      #pragma unroll
      for (int j = 0; j < 16; j++){
        int e = j*256 + tid;
        int b = e >> 7, c8 = e & 127;
        *(u64*)(hX + b*1024 + ((c8*8) ^ ((b & 7) << 4))) = xd[j];
      }
    } else {
      // need h1[t] complete (c1 >= 32(t+1)) and own layer at step t
      wait2(c1, (u32)(NWG*(t+1)), c2, (t > 0) ? (u32)(NWG*t) : 0u, budget);
      stage_h(h1r + (size_t)(t & (RING-1))*HS, hX, tid);
      if (t > 0) stage_h(h2r + (size_t)((t-1) & 1)*HS, hH, tid);
    }
    __syncthreads();

    // ---- MFMA phase: input-projection term (hX) + recurrent term (hH) ----
    f32x4 e0 = {0.f,0.f,0.f,0.f}, e1 = {0.f,0.f,0.f,0.f};
    #pragma unroll
    for (int kk = 0; kk < 16; kk++){
      int byt = (lane & 15)*1024 + ((kk*64 + (lane>>4)*16) ^ (((lane & 15) & 7) << 4));
      s16x8 f0 = *(const s16x8*)(hX + byt);
      s16x8 f1 = *(const s16x8*)(hX + byt + 16*1024);
      e0 = __builtin_amdgcn_mfma_f32_16x16x32_bf16(aih[kk], f0, e0, 0, 0, 0);
      e1 = __builtin_amdgcn_mfma_f32_16x16x32_bf16(aih[kk], f1, e1, 0, 0, 0);
    }
    if (t > 0){
      #pragma unroll
      for (int kk = 0; kk < 16; kk++){
        int byt = (lane & 15)*1024 + ((kk*64 + (lane>>4)*16) ^ (((lane & 15) & 7) << 4));
        s16x8 f0 = *(const s16x8*)(hH + byt);
        s16x8 f1 = *(const s16x8*)(hH + byt + 16*1024);
        e0 = __builtin_amdgcn_mfma_f32_16x16x32_bf16(ahh[kk], f0, e0, 0, 0, 0);
        e1 = __builtin_amdgcn_mfma_f32_16x16x32_bf16(ahh[kk], f1, e1, 0, 0, 0);
      }
    }

    // gates: e[r] = gate q=r of col oc (i,f,g,o); e0 -> b0, e1 -> b1
    float ig = sigm (e0[0] + b4[0]), fg = sigm (e0[1] + b4[1]);
    float gg = ftanh(e0[2] + b4[2]), og = sigm (e0[3] + b4[3]);
    c0 = fg*c0 + ig*gg;
    float hv0 = og * ftanh(c0);
    ig = sigm (e1[0] + b4[0]); fg = sigm (e1[1] + b4[1]);
    gg = ftanh(e1[2] + b4[2]); og = sigm (e1[3] + b4[3]);
    cst1 = fg*cst1 + ig*gg;
    float hv1 = og * ftanh(cst1);

    // pack col pairs (even col-group lanes pack partner lane+16) -> 4B words
    u16 hh0 = f2bf(hv0), hh1 = f2bf(hv1);
    u32 p0 = (u32)hh0 | (((u32)__shfl((int)hh0, (lane + 16) & 63) & 0xffffu) << 16);
    u32 p1 = (u32)hh1 | (((u32)__shfl((int)hh1, (lane + 16) & 63) & 0xffffu) << 16);
    u16* dst = isL2 ? (h2r + (size_t)(t & 1)*HS)
                    : (h1r + (size_t)(t & (RING-1))*HS);
    if (((lane >> 4) & 1) == 0){
      __hip_atomic_store((u32*)(dst + (size_t)b0*DD + oc), p0,
                         __ATOMIC_RELAXED, __HIP_MEMORY_SCOPE_AGENT);
      __hip_atomic_store((u32*)(dst + (size_t)b1*DD + oc), p1,
                         __ATOMIC_RELAXED, __HIP_MEMORY_SCOPE_AGENT);
      if (isL2){
        *(u32*)(h_seq2 + ((size_t)b0*SS + t)*DD + oc) = p0;
        *(u32*)(h_seq2 + ((size_t)b1*SS + t)*DD + oc) = p1;
      }
    }
    asm volatile("s_waitcnt vmcnt(0)" ::: "memory");  // h stores at coherence pt
    __syncthreads();                                   // all waves drained
    if (tid == 0) atomicAdd(isL2 ? c2 : c1, 1u);       // device-scope publish
  }
}

// ---------------- ragged mean-pool + span head ----------------------------
__global__ __launch_bounds__(64) void k_pool(const u16* __restrict__ h_seq,
                                             const int* __restrict__ twid,
                                             const float* __restrict__ Wout,
                                             const float* __restrict__ bout,
                                             float* __restrict__ out){
  int bw = blockIdx.x;
  int b = bw >> 8, w = bw & 255;
  const int* tw = twid + b*SS;
  __shared__ int s_lo, s_hi;
  if (threadIdx.x == 0){
    int l = 0, r = SS;
    while (l < r){ int m = (l + r) >> 1; if (tw[m] < w) l = m + 1; else r = m; }
    s_lo = l;
    r = SS;
    while (l < r){ int m = (l + r) >> 1; if (tw[m] < w + 1) l = m + 1; else r = m; }
    s_hi = l;
  }
  __syncthreads();
  int lo = s_lo, hi = s_hi, cnt = hi - lo;
  int lane = threadIdx.x;
  float p0 = 0.f, p1 = 0.f;
  if (cnt > 0){
    float sum[8] = {0.f,0.f,0.f,0.f,0.f,0.f,0.f,0.f};
    for (int t = lo; t < hi; t++){
      const u16* hp = h_seq + ((size_t)b*SS + t)*DD + lane*8;
      int4 v = *(const int4*)hp;
      const u16* u = (const u16*)&v;
      #pragma unroll
      for (int j = 0; j < 8; j++) sum[j] += bf2f(u[j]);
    }
    float inv = 1.f/(float)cnt;
    #pragma unroll
    for (int j = 0; j < 8; j++){
      float pv = sum[j]*inv;
      int d = lane*8 + j;
      p0 += pv * Wout[d];
      p1 += pv * Wout[DD + d];
    }
  }
  #pragma unroll
  for (int off = 32; off; off >>= 1){
    p0 += __shfl_down(p0, off);
    p1 += __shfl_down(p1, off);
  }
  if (lane == 0){
    out[bw*2 + 0] = p0 + bout[0];
    out[bw*2 + 1] = p1 + bout[1];
  }
}

// ---------------- NLL loss over 8192 spans --------------------------------
__global__ __launch_bounds__(256) void k_loss(const float* __restrict__ logits,
                                              const int* __restrict__ labels,
                                              float* __restrict__ out_loss){
  __shared__ float red[256];
  float acc = 0.f;
  for (int i = threadIdx.x; i < BB*MAXW; i += 256){
    float z0 = logits[i*2], z1 = logits[i*2 + 1];
    float m = fmaxf(z0, z1);
    float lse = m + __logf(__expf(z0 - m) + __expf(z1 - m));
    float zl = labels[i] ? z1 : z0;
    acc += (lse - zl);
  }
  red[threadIdx.x] = acc;
  __syncthreads();
  for (int s2 = 128; s2; s2 >>= 1){
    if (threadIdx.x < s2) red[threadIdx.x] += red[threadIdx.x + s2];
    __syncthreads();
  }
  if (threadIdx.x == 0) out_loss[0] = red[0] / (float)(BB*MAXW);
}

extern "C" void kernel_launch(void* const* d_in, const int* in_sizes, int n_in,
                              void* d_out, int out_size, void* d_ws, size_t ws_size,
                              hipStream_t stream){
  (void)in_sizes; (void)n_in; (void)out_size; (void)ws_size;
  const int*   x      = (const int*)  d_in[0];
  const int*   labels = (const int*)  d_in[1];
  const int*   twid   = (const int*)  d_in[2];
  const float* emb    = (const float*)d_in[3];
  const float* Wih    = (const float*)d_in[4];
  const float* Whh    = (const float*)d_in[5];
  const float* bih    = (const float*)d_in[6];
  const float* bhh    = (const float*)d_in[7];
  const float* Wout   = (const float*)d_in[8];
  const float* bout   = (const float*)d_in[9];
  float* out = (float*)d_out;

  char* ws = (char*)d_ws;
  size_t off = 0;
  u16*   h_io   = (u16*)  (ws + off); off += (size_t)BB*SS*DD*2;    // 32 MB
  u16*   h_seq2 = (u16*)  (ws + off); off += (size_t)BB*SS*DD*2;    // 32 MB
  u16*   Wih_b  = (u16*)  (ws + off); off += (size_t)2*G4*DD*2;     // 4 MB
  u16*   Whh_b  = (u16*)  (ws + off); off += (size_t)2*G4*DD*2;     // 4 MB
  float* biasp  = (float*)(ws + off); off += (size_t)2*G4*4;        // 16 KB
  u16*   h1r    = (u16*)  (ws + off); off += (size_t)RING*HS*2;     // 256 KB
  u16*   h2r    = (u16*)  (ws + off); off += (size_t)2*HS*2;        // 64 KB
  u32*   flags  = (u32*)  (ws + off); off += 1024;
  // total ~72.3 MB

  k_prep<<<2048, 256, 0, stream>>>(Wih, Whh, bih, bhh, Wih_b, Whh_b, biasp);
  k_embed<<<BB*SS, 256, 0, stream>>>(x, emb, h_io);

  hipMemsetAsync(flags, 0, 1024, stream);

  k_recur2<<<2*NWG, 256, 0, stream>>>(h_io, Wih_b, Whh_b, biasp,
                                      h1r, h2r, flags, h_seq2);

  k_pool<<<BB*MAXW, 64, 0, stream>>>(h_seq2, twid, Wout, bout, out);
  k_loss<<<1, 256, 0, stream>>>(out, labels, out + BB*MAXW*2);
}

// Round 8
// 5182.792 us; speedup vs baseline: 4.9574x; 1.0656x over previous
//
#include <hip/hip_runtime.h>
#include <hip/hip_fp16.h>

typedef unsigned short u16;
typedef unsigned int u32;
typedef unsigned long long u64;
typedef short s16x8 __attribute__((ext_vector_type(8)));
typedef float f32x4 __attribute__((ext_vector_type(4)));

#define BB   32
#define SS   1024
#define DD   512
#define G4   2048
#define MAXW 256
#define NWG  32                 // workgroups per layer
#define RING 8                  // h1 ring slots (pipeline window)
#define HS   (BB*DD)            // u16 elements per h slab (32KB)

__device__ __forceinline__ u16 f2bf(float f){
  unsigned int u = __float_as_uint(f);
  u += 0x7fff + ((u >> 16) & 1);           // RNE
  return (u16)(u >> 16);
}
__device__ __forceinline__ float bf2f(u16 h){
  return __uint_as_float(((unsigned int)h) << 16);
}
__device__ __forceinline__ float sigm(float x){ return 1.f/(1.f + __expf(-x)); }
__device__ __forceinline__ float ftanh(float x){
  float ax = fabsf(x);
  float e = __expf(-2.f*ax);               // in (0,1], never overflows
  float t = (1.f - e)/(1.f + e);
  return copysignf(t, x);
}

// ---------------- prep: fp32 weights -> bf16; fused permuted bias ----------
// bias_perm[l][n] = b_ih[l][g]+b_hh[l][g], g = (n&3)*512 + (n>>2) (gate-minor)
__global__ void k_prep(const float* __restrict__ Wih, const float* __restrict__ Whh,
                       const float* __restrict__ bih, const float* __restrict__ bhh,
                       u16* __restrict__ Wih_b, u16* __restrict__ Whh_b,
                       float* __restrict__ biasp){
  long i = (long)blockIdx.x*blockDim.x + threadIdx.x;
  long n = 2l*G4*DD;
  long stride = (long)gridDim.x*blockDim.x;
  for (long k = i; k < n; k += stride){
    Wih_b[k] = f2bf(Wih[k]);
    Whh_b[k] = f2bf(Whh[k]);
  }
  for (long k = i; k < 2*G4; k += stride){
    int lyr = (int)(k / G4), nn = (int)(k % G4);
    int col = nn >> 2, q = nn & 3;
    int g = q*DD + col;
    biasp[k] = bih[lyr*G4 + g] + bhh[lyr*G4 + g];
  }
}

// ---------------- embedding gather -> bf16 [B*S][D] ------------------------
__global__ void k_embed(const int* __restrict__ x, const float* __restrict__ emb,
                        u16* __restrict__ out){
  int bs = blockIdx.x;
  int tok = x[bs];
  const float* src = emb + (size_t)tok * DD;
  u16* dst = out + (size_t)bs * DD;
  for (int d = threadIdx.x; d < DD; d += blockDim.x) dst[d] = f2bf(src[d]);
}

// ---- wait until all lanes see *p1>=n1 and *p2>=n2 (wave-uniform loads) ----
// budget is TOTAL across the kernel: a broken protocol fails loudly in ~1s
// with wrong output instead of hanging the harness.
__device__ __forceinline__ void wait2(const u32* p1, u32 n1,
                                      const u32* p2, u32 n2, int& budget){
  if (n1 == 0u && n2 == 0u) return;
  while (budget > 0){
    u32 v1 = n1 ? __hip_atomic_load(p1, __ATOMIC_RELAXED, __HIP_MEMORY_SCOPE_AGENT)
                : 0xffffffffu;
    u32 v2 = n2 ? __hip_atomic_load(p2, __ATOMIC_RELAXED, __HIP_MEMORY_SCOPE_AGENT)
                : 0xffffffffu;
    int ok = (v1 >= n1) && (v2 >= n2);
    if (__all(ok)) break;
    budget--;
    __builtin_amdgcn_s_sleep(1);
  }
}

// ---- stage a 32x512 bf16 slab (32KB) into XOR-swizzled LDS ---------------
// 256 threads x 16 x 8B agent-atomic loads (MALL-coherent, R2/R7-proven).
__device__ __forceinline__ void stage_h(const u16* slab, char* lds, int tid){
  u64 d[16];
  #pragma unroll
  for (int j = 0; j < 16; j++)
    d[j] = __hip_atomic_load((const u64*)slab + j*256 + tid,
                             __ATOMIC_RELAXED, __HIP_MEMORY_SCOPE_AGENT);
  #pragma unroll
  for (int j = 0; j < 16; j++){
    int e = j*256 + tid;
    int b = e >> 7, c8 = e & 127;
    *(u64*)(lds + b*1024 + ((c8*8) ^ ((b & 7) << 4))) = d[j];
  }
}

// fragment byte offset in a staged slab for (lane, kk)
#define FRAG_BYT(kk) ((lane & 15)*1024 + (((kk)*64 + (lane>>4)*16) ^ (((lane & 15) & 7) << 4)))

// ---------------- fused 2-layer persistent LSTM recurrence ----------------
// 64 WGs x 256 threads (all co-resident). WGs 0..31: layer 1 (W_ih1@x_t on
// the fly); 32..63: layer 2 (pipelined 1 step behind, W_ih2@h1_t on the fly).
// WG id owns permuted gate-rows [64id,64id+64) = h-cols [16id,16id+16).
// Weights REGISTER-PINNED via asm barrier (defeats compiler load-sinking
// that re-streamed 128KB/WG/step from L2 in R7 — VGPR_Count 148 proved it).
// Independent MFMA terms (L1: x-term, L2: own-recurrent term) are computed
// BEFORE the cross-layer wait so they hide under publish-propagate latency.
// Sync (R7-proven): one monotonic counter per layer; publish = h stores ->
// vmcnt(0) -> barrier -> tid0 atomicAdd; wait = wave-uniform counter polls.
// h1: 8-slot ring + backpressure (c2 >= 32(t-7)); h2: 2-slot ring.
__global__ __launch_bounds__(256, 1) void k_recur2(
    const u16* __restrict__ h_io,
    const u16* __restrict__ Wih_b,
    const u16* __restrict__ Whh_b,
    const float* __restrict__ biasp,
    u16* __restrict__ h1r,
    u16* __restrict__ h2r,
    u32* __restrict__ flags,
    u16* __restrict__ h_seq2){
  __shared__ char hX[32768];               // L1: x tile   | L2: h1 tile
  __shared__ char hH[32768];               // L1: h1 tile  | L2: h2 tile
  const int tid = threadIdx.x;
  const int lane = tid & 63, wv = tid >> 6;
  const int wg = blockIdx.x;
  const bool isL2 = wg >= NWG;
  const int id = wg & (NWG - 1);

  u32* c1 = flags;                         // layer-1 progress (own 128B line)
  u32* c2 = flags + 64;                    // layer-2 progress

  // weight A-fragments: perm gate-row pa = id*64 + wv*16 + (lane&15)
  const int pa = id*64 + wv*16 + (lane & 15);
  const size_t arow = (size_t)((pa & 3)*DD + (pa >> 2))*DD;
  const int koff = (lane >> 4)*8;
  const size_t lyrOff = isL2 ? (size_t)G4*DD : 0;
  s16x8 ahh[16], aih[16];
  #pragma unroll
  for (int kk = 0; kk < 16; kk++){
    ahh[kk] = *(const s16x8*)(Whh_b + lyrOff + arow + kk*32 + koff);
    aih[kk] = *(const s16x8*)(Wih_b + lyrOff + arow + kk*32 + koff);
  }
  // pin fragments in VGPRs: opaque to the optimizer => loads cannot be sunk
  // into the t-loop (R7: VGPR=148 showed per-step L2 weight re-streaming)
  #pragma unroll
  for (int kk = 0; kk < 16; kk++){
    asm volatile("" : "+v"(ahh[kk]));
    asm volatile("" : "+v"(aih[kk]));
  }

  const int oc = id*16 + wv*4 + (lane >> 4);      // lane's h column
  const int b0 = lane & 15, b1 = b0 + 16;         // lane's two batches
  const f32x4 b4 = *(const f32x4*)(biasp + (isL2 ? G4 : 0) + oc*4);
  float c0 = 0.f, cst1 = 0.f;
  int budget = 1 << 22;                    // total spin budget (anti-hang)

  if (!isL2){
    // ============================ layer 1 ============================
    for (int t = 0; t < SS; t++){
      // ---- independent phase: stage x_t, compute x-term (pre-wait) ----
      u64 xd[16];
      #pragma unroll
      for (int j = 0; j < 16; j++){
        int e = j*256 + tid;
        xd[j] = *((const u64*)h_io + ((size_t)(e >> 7)*SS + t)*128 + (e & 127));
      }
      #pragma unroll
      for (int j = 0; j < 16; j++){
        int e = j*256 + tid;
        int b = e >> 7, c8 = e & 127;
        *(u64*)(hX + b*1024 + ((c8*8) ^ ((b & 7) << 4))) = xd[j];
      }
      __syncthreads();                     // A: hX ready
      f32x4 e0 = {0.f,0.f,0.f,0.f}, e1 = {0.f,0.f,0.f,0.f};
      #pragma unroll
      for (int kk = 0; kk < 16; kk++){
        int byt = FRAG_BYT(kk);
        s16x8 f0 = *(const s16x8*)(hX + byt);
        s16x8 f1 = *(const s16x8*)(hX + byt + 16*1024);
        e0 = __builtin_amdgcn_mfma_f32_16x16x32_bf16(aih[kk], f0, e0, 0, 0, 0);
        e1 = __builtin_amdgcn_mfma_f32_16x16x32_bf16(aih[kk], f1, e1, 0, 0, 0);
      }
      // ---- dependent phase: wait h1[t-1], recurrent term ----
      u32 n1 = (t > 0) ? (u32)(NWG*t) : 0u;
      u32 n2 = (t >= RING) ? (u32)(NWG*(t - RING + 1)) : 0u;
      wait2(c1, n1, c2, n2, budget);
      if (t > 0){
        stage_h(h1r + (size_t)((t-1) & (RING-1))*HS, hH, tid);
        __syncthreads();                   // B: hH ready
        #pragma unroll
        for (int kk = 0; kk < 16; kk++){
          int byt = FRAG_BYT(kk);
          s16x8 f0 = *(const s16x8*)(hH + byt);
          s16x8 f1 = *(const s16x8*)(hH + byt + 16*1024);
          e0 = __builtin_amdgcn_mfma_f32_16x16x32_bf16(ahh[kk], f0, e0, 0, 0, 0);
          e1 = __builtin_amdgcn_mfma_f32_16x16x32_bf16(ahh[kk], f1, e1, 0, 0, 0);
        }
      }
      // ---- gates + publish ----
      float ig = sigm (e0[0] + b4[0]), fg = sigm (e0[1] + b4[1]);
      float gg = ftanh(e0[2] + b4[2]), og = sigm (e0[3] + b4[3]);
      c0 = fg*c0 + ig*gg;
      float hv0 = og * ftanh(c0);
      ig = sigm (e1[0] + b4[0]); fg = sigm (e1[1] + b4[1]);
      gg = ftanh(e1[2] + b4[2]); og = sigm (e1[3] + b4[3]);
      cst1 = fg*cst1 + ig*gg;
      float hv1 = og * ftanh(cst1);
      u16 hh0 = f2bf(hv0), hh1 = f2bf(hv1);
      u32 p0 = (u32)hh0 | (((u32)__shfl((int)hh0, (lane + 16) & 63) & 0xffffu) << 16);
      u32 p1 = (u32)hh1 | (((u32)__shfl((int)hh1, (lane + 16) & 63) & 0xffffu) << 16);
      u16* dst = h1r + (size_t)(t & (RING-1))*HS;
      if (((lane >> 4) & 1) == 0){
        __hip_atomic_store((u32*)(dst + (size_t)b0*DD + oc), p0,
                           __ATOMIC_RELAXED, __HIP_MEMORY_SCOPE_AGENT);
        __hip_atomic_store((u32*)(dst + (size_t)b1*DD + oc), p1,
                           __ATOMIC_RELAXED, __HIP_MEMORY_SCOPE_AGENT);
      }
      asm volatile("s_waitcnt vmcnt(0)" ::: "memory");
      __syncthreads();                     // C: all stores drained, LDS free
      if (tid == 0) atomicAdd(c1, 1u);
    }
  } else {
    // ============================ layer 2 ============================
    for (int t = 0; t < SS; t++){
      // ---- independent phase: own-layer lockstep + recurrent term ----
      f32x4 e0 = {0.f,0.f,0.f,0.f}, e1 = {0.f,0.f,0.f,0.f};
      if (t > 0){
        wait2(c2, (u32)(NWG*t), c2, 0u, budget);   // peers finished t-1 (fast)
        stage_h(h2r + (size_t)((t-1) & 1)*HS, hH, tid);
        __syncthreads();                   // A: hH ready
        #pragma unroll
        for (int kk = 0; kk < 16; kk++){
          int byt = FRAG_BYT(kk);
          s16x8 f0 = *(const s16x8*)(hH + byt);
          s16x8 f1 = *(const s16x8*)(hH + byt + 16*1024);
          e0 = __builtin_amdgcn_mfma_f32_16x16x32_bf16(ahh[kk], f0, e0, 0, 0, 0);
          e1 = __builtin_amdgcn_mfma_f32_16x16x32_bf16(ahh[kk], f1, e1, 0, 0, 0);
        }
      }
      // ---- dependent phase: wait h1[t], input-projection term ----
      wait2(c1, (u32)(NWG*(t+1)), c2, 0u, budget);
      stage_h(h1r + (size_t)(t & (RING-1))*HS, hX, tid);
      __syncthreads();                     // B: hX ready
      #pragma unroll
      for (int kk = 0; kk < 16; kk++){
        int byt = FRAG_BYT(kk);
        s16x8 f0 = *(const s16x8*)(hX + byt);
        s16x8 f1 = *(const s16x8*)(hX + byt + 16*1024);
        e0 = __builtin_amdgcn_mfma_f32_16x16x32_bf16(aih[kk], f0, e0, 0, 0, 0);
        e1 = __builtin_amdgcn_mfma_f32_16x16x32_bf16(aih[kk], f1, e1, 0, 0, 0);
      }
      // ---- gates + publish ----
      float ig = sigm (e0[0] + b4[0]), fg = sigm (e0[1] + b4[1]);
      float gg = ftanh(e0[2] + b4[2]), og = sigm (e0[3] + b4[3]);
      c0 = fg*c0 + ig*gg;
      float hv0 = og * ftanh(c0);
      ig = sigm (e1[0] + b4[0]); fg = sigm (e1[1] + b4[1]);
      gg = ftanh(e1[2] + b4[2]); og = sigm (e1[3] + b4[3]);
      cst1 = fg*cst1 + ig*gg;
      float hv1 = og * ftanh(cst1);
      u16 hh0 = f2bf(hv0), hh1 = f2bf(hv1);
      u32 p0 = (u32)hh0 | (((u32)__shfl((int)hh0, (lane + 16) & 63) & 0xffffu) << 16);
      u32 p1 = (u32)hh1 | (((u32)__shfl((int)hh1, (lane + 16) & 63) & 0xffffu) << 16);
      u16* dst = h2r + (size_t)(t & 1)*HS;
      if (((lane >> 4) & 1) == 0){
        __hip_atomic_store((u32*)(dst + (size_t)b0*DD + oc), p0,
                           __ATOMIC_RELAXED, __HIP_MEMORY_SCOPE_AGENT);
        __hip_atomic_store((u32*)(dst + (size_t)b1*DD + oc), p1,
                           __ATOMIC_RELAXED, __HIP_MEMORY_SCOPE_AGENT);
        *(u32*)(h_seq2 + ((size_t)b0*SS + t)*DD + oc) = p0;
        *(u32*)(h_seq2 + ((size_t)b1*SS + t)*DD + oc) = p1;
      }
      asm volatile("s_waitcnt vmcnt(0)" ::: "memory");
      __syncthreads();                     // C
      if (tid == 0) atomicAdd(c2, 1u);
    }
  }
}

// ---------------- ragged mean-pool + span head ----------------------------
__global__ __launch_bounds__(64) void k_pool(const u16* __restrict__ h_seq,
                                             const int* __restrict__ twid,
                                             const float* __restrict__ Wout,
                                             const float* __restrict__ bout,
                                             float* __restrict__ out){
  int bw = blockIdx.x;
  int b = bw >> 8, w = bw & 255;
  const int* tw = twid + b*SS;
  __shared__ int s_lo, s_hi;
  if (threadIdx.x == 0){
    int l = 0, r = SS;
    while (l < r){ int m = (l + r) >> 1; if (tw[m] < w) l = m + 1; else r = m; }
    s_lo = l;
    r = SS;
    while (l < r){ int m = (l + r) >> 1; if (tw[m] < w + 1) l = m + 1; else r = m; }
    s_hi = l;
  }
  __syncthreads();
  int lo = s_lo, hi = s_hi, cnt = hi - lo;
  int lane = threadIdx.x;
  float p0 = 0.f, p1 = 0.f;
  if (cnt > 0){
    float sum[8] = {0.f,0.f,0.f,0.f,0.f,0.f,0.f,0.f};
    for (int t = lo; t < hi; t++){
      const u16* hp = h_seq + ((size_t)b*SS + t)*DD + lane*8;
      int4 v = *(const int4*)hp;
      const u16* u = (const u16*)&v;
      #pragma unroll
      for (int j = 0; j < 8; j++) sum[j] += bf2f(u[j]);
    }
    float inv = 1.f/(float)cnt;
    #pragma unroll
    for (int j = 0; j < 8; j++){
      float pv = sum[j]*inv;
      int d = lane*8 + j;
      p0 += pv * Wout[d];
      p1 += pv * Wout[DD + d];
    }
  }
  #pragma unroll
  for (int off = 32; off; off >>= 1){
    p0 += __shfl_down(p0, off);
    p1 += __shfl_down(p1, off);
  }
  if (lane == 0){
    out[bw*2 + 0] = p0 + bout[0];
    out[bw*2 + 1] = p1 + bout[1];
  }
}

// ---------------- NLL loss over 8192 spans --------------------------------
__global__ __launch_bounds__(256) void k_loss(const float* __restrict__ logits,
                                              const int* __restrict__ labels,
                                              float* __restrict__ out_loss){
  __shared__ float red[256];
  float acc = 0.f;
  for (int i = threadIdx.x; i < BB*MAXW; i += 256){
    float z0 = logits[i*2], z1 = logits[i*2 + 1];
    float m = fmaxf(z0, z1);
    float lse = m + __logf(__expf(z0 - m) + __expf(z1 - m));
    float zl = labels[i] ? z1 : z0;
    acc += (lse - zl);
  }
  red[threadIdx.x] = acc;
  __syncthreads();
  for (int s2 = 128; s2; s2 >>= 1){
    if (threadIdx.x < s2) red[threadIdx.x] += red[threadIdx.x + s2];
    __syncthreads();
  }
  if (threadIdx.x == 0) out_loss[0] = red[0] / (float)(BB*MAXW);
}

extern "C" void kernel_launch(void* const* d_in, const int* in_sizes, int n_in,
                              void* d_out, int out_size, void* d_ws, size_t ws_size,
                              hipStream_t stream){
  (void)in_sizes; (void)n_in; (void)out_size; (void)ws_size;
  const int*   x      = (const int*)  d_in[0];
  const int*   labels = (const int*)  d_in[1];
  const int*   twid   = (const int*)  d_in[2];
  const float* emb    = (const float*)d_in[3];
  const float* Wih    = (const float*)d_in[4];
  const float* Whh    = (const float*)d_in[5];
  const float* bih    = (const float*)d_in[6];
  const float* bhh    = (const float*)d_in[7];
  const float* Wout   = (const float*)d_in[8];
  const float* bout   = (const float*)d_in[9];
  float* out = (float*)d_out;

  char* ws = (char*)d_ws;
  size_t off = 0;
  u16*   h_io   = (u16*)  (ws + off); off += (size_t)BB*SS*DD*2;    // 32 MB
  u16*   h_seq2 = (u16*)  (ws + off); off += (size_t)BB*SS*DD*2;    // 32 MB
  u16*   Wih_b  = (u16*)  (ws + off); off += (size_t)2*G4*DD*2;     // 4 MB
  u16*   Whh_b  = (u16*)  (ws + off); off += (size_t)2*G4*DD*2;     // 4 MB
  float* biasp  = (float*)(ws + off); off += (size_t)2*G4*4;        // 16 KB
  u16*   h1r    = (u16*)  (ws + off); off += (size_t)RING*HS*2;     // 256 KB
  u16*   h2r    = (u16*)  (ws + off); off += (size_t)2*HS*2;        // 64 KB
  u32*   flags  = (u32*)  (ws + off); off += 1024;
  // total ~72.3 MB

  k_prep<<<2048, 256, 0, stream>>>(Wih, Whh, bih, bhh, Wih_b, Whh_b, biasp);
  k_embed<<<BB*SS, 256, 0, stream>>>(x, emb, h_io);

  hipMemsetAsync(flags, 0, 1024, stream);

  k_recur2<<<2*NWG, 256, 0, stream>>>(h_io, Wih_b, Whh_b, biasp,
                                      h1r, h2r, flags, h_seq2);

  k_pool<<<BB*MAXW, 64, 0, stream>>>(h_seq2, twid, Wout, bout, out);
  k_loss<<<1, 256, 0, stream>>>(out, labels, out + BB*MAXW*2);
}